// Round 1
// baseline (346.685 us; speedup 1.0000x reference)
//
#include <hip/hip_runtime.h>

#define NN      4096
#define FEAT    512
#define NHID    64
#define NHEADS  8
#define NCLS    16
#define MAXDEG  128
#define ALPHA   0.2f

// ---------------------------------------------------------------------------
// out[i,:] = in[i,:] + adj_ad[i,:] @ rel   ([N,64]@[64,512])
// block = 128 threads, one row per block, each thread owns 4 features.
__global__ __launch_bounds__(128) void relmm_add_kernel(
    const float* __restrict__ in, const float* __restrict__ adj_ad,
    const float* __restrict__ rel, float* __restrict__ out) {
    int i = blockIdx.x;
    int t = threadIdx.x;            // 0..127
    __shared__ float sa[64];
    if (t < 64) sa[t] = adj_ad[i * 64 + t];
    __syncthreads();
    float4 acc = ((const float4*)(in + (size_t)i * FEAT))[t];
    for (int r = 0; r < 64; ++r) {
        float a = sa[r];
        float4 rv = ((const float4*)(rel + r * FEAT))[t];
        acc.x += a * rv.x; acc.y += a * rv.y;
        acc.z += a * rv.z; acc.w += a * rv.w;
    }
    ((float4*)(out + (size_t)i * FEAT))[t] = acc;
}

// ---------------------------------------------------------------------------
// Wcat[k*512 + h*64 + f] = W_heads[h][k][f]   (head-concat column layout)
__global__ void wcat_kernel(const float* __restrict__ Wh, float* __restrict__ Wcat) {
    int idx = blockIdx.x * 256 + threadIdx.x;     // 0 .. 262143
    int k = idx >> 9;
    int c = idx & 511;
    int h = c >> 6;
    int f = c & 63;
    Wcat[idx] = Wh[h * (512 * 64) + k * 64 + f];
}

// ---------------------------------------------------------------------------
// C[4096,512] = A[4096,512] @ B[512,512], all row-major fp32.
// 64x64 tile per block, BK=16, 256 threads, 4x4 micro-tile per thread.
__global__ __launch_bounds__(256) void sgemm_kernel(
    const float* __restrict__ A, const float* __restrict__ B, float* __restrict__ C) {
    __shared__ float As[16][64];
    __shared__ float Bs[16][64];
    int bm = blockIdx.x * 64;
    int bn = blockIdx.y * 64;
    int tid = threadIdx.x;
    int tx = tid & 15;    // col group
    int ty = tid >> 4;    // row group
    float acc[4][4] = {};
    for (int k0 = 0; k0 < FEAT; k0 += 16) {
        int m  = tid >> 2;
        int kk = (tid & 3) * 4;
        float4 av = *(const float4*)(A + (size_t)(bm + m) * FEAT + k0 + kk);
        As[kk + 0][m] = av.x; As[kk + 1][m] = av.y;
        As[kk + 2][m] = av.z; As[kk + 3][m] = av.w;
        int kb = tid >> 4;
        int nb = (tid & 15) * 4;
        float4 bv = *(const float4*)(B + (size_t)(k0 + kb) * FEAT + bn + nb);
        Bs[kb][nb + 0] = bv.x; Bs[kb][nb + 1] = bv.y;
        Bs[kb][nb + 2] = bv.z; Bs[kb][nb + 3] = bv.w;
        __syncthreads();
        for (int k = 0; k < 16; ++k) {
            float a0 = As[k][ty * 4 + 0], a1 = As[k][ty * 4 + 1];
            float a2 = As[k][ty * 4 + 2], a3 = As[k][ty * 4 + 3];
            float b0 = Bs[k][tx * 4 + 0], b1 = Bs[k][tx * 4 + 1];
            float b2 = Bs[k][tx * 4 + 2], b3 = Bs[k][tx * 4 + 3];
            acc[0][0] += a0 * b0; acc[0][1] += a0 * b1; acc[0][2] += a0 * b2; acc[0][3] += a0 * b3;
            acc[1][0] += a1 * b0; acc[1][1] += a1 * b1; acc[1][2] += a1 * b2; acc[1][3] += a1 * b3;
            acc[2][0] += a2 * b0; acc[2][1] += a2 * b1; acc[2][2] += a2 * b2; acc[2][3] += a2 * b3;
            acc[3][0] += a3 * b0; acc[3][1] += a3 * b1; acc[3][2] += a3 * b2; acc[3][3] += a3 * b3;
        }
        __syncthreads();
    }
    for (int r = 0; r < 4; ++r) {
        float4 v = make_float4(acc[r][0], acc[r][1], acc[r][2], acc[r][3]);
        *(float4*)(C + (size_t)(bm + ty * 4 + r) * FEAT + bn + tx * 4) = v;
    }
}

// ---------------------------------------------------------------------------
// f1[h,i] = sum_f H[i, h*64+f]*a1[h,f];  f2 likewise. One wave per (i,h).
__global__ __launch_bounds__(256) void headdot_kernel(
    const float* __restrict__ H, const float* __restrict__ a1,
    const float* __restrict__ a2, float* __restrict__ f1, float* __restrict__ f2) {
    int i = blockIdx.x;
    int w = threadIdx.x >> 6;
    int l = threadIdx.x & 63;
    int h = blockIdx.y * 4 + w;
    float v = H[(size_t)i * FEAT + h * 64 + l];
    float s1 = v * a1[h * 64 + l];
    float s2 = v * a2[h * 64 + l];
    for (int off = 32; off; off >>= 1) {
        s1 += __shfl_down(s1, off);
        s2 += __shfl_down(s2, off);
    }
    if (l == 0) { f1[h * NN + i] = s1; f2[h * NN + i] = s2; }
}

// ---------------------------------------------------------------------------
// f1o[i] = H[i,:] @ a1_out; f2o likewise (F=512). One block (256 thr) per row.
__global__ __launch_bounds__(256) void rowdot_kernel(
    const float* __restrict__ H, const float* __restrict__ a1,
    const float* __restrict__ a2, float* __restrict__ f1, float* __restrict__ f2) {
    int i = blockIdx.x;
    int t = threadIdx.x;
    float v0 = H[(size_t)i * FEAT + t];
    float v1 = H[(size_t)i * FEAT + 256 + t];
    float s1 = v0 * a1[t] + v1 * a1[256 + t];
    float s2 = v0 * a2[t] + v1 * a2[256 + t];
    for (int off = 32; off; off >>= 1) {
        s1 += __shfl_down(s1, off);
        s2 += __shfl_down(s2, off);
    }
    __shared__ float r1[4], r2[4];
    if ((t & 63) == 0) { r1[t >> 6] = s1; r2[t >> 6] = s2; }
    __syncthreads();
    if (t == 0) {
        f1[i] = r1[0] + r1[1] + r1[2] + r1[3];
        f2[i] = r2[0] + r2[1] + r2[2] + r2[3];
    }
}

// ---------------------------------------------------------------------------
// CSR build (unordered cols; softmax/accum are order-independent sums).
__global__ __launch_bounds__(256) void csr_kernel(
    const float* __restrict__ adj, int* __restrict__ deg, int* __restrict__ cols) {
    int i = blockIdx.x;
    __shared__ int cnt;
    if (threadIdx.x == 0) cnt = 0;
    __syncthreads();
    const float* row = adj + (size_t)i * NN;
    for (int j = threadIdx.x; j < NN; j += 256) {
        if (row[j] > 0.0f) {
            int p = atomicAdd(&cnt, 1);
            if (p < MAXDEG) cols[i * MAXDEG + p] = j;
        }
    }
    __syncthreads();
    if (threadIdx.x == 0) deg[i] = cnt > MAXDEG ? MAXDEG : cnt;
}

// ---------------------------------------------------------------------------
// Layer-1 sparse attention + ELU. Block = 512 threads (8 waves = 8 heads),
// one node per block, lane = hidden feature.
__global__ __launch_bounds__(512) void att1_kernel(
    const float* __restrict__ H, const float* __restrict__ f1,
    const float* __restrict__ f2, const int* __restrict__ deg,
    const int* __restrict__ cols, float* __restrict__ out) {
    int i = blockIdx.x;
    int h = threadIdx.x >> 6;
    int l = threadIdx.x & 63;
    __shared__ int jl[MAXDEG];
    __shared__ float se[NHEADS][MAXDEG];
    __shared__ int sdeg;
    if (threadIdx.x == 0) sdeg = deg[i];
    __syncthreads();
    int d = sdeg;
    for (int k = threadIdx.x; k < d; k += 512) jl[k] = cols[i * MAXDEG + k];
    __syncthreads();
    float fi = f1[h * NN + i];
    // pass 1: scores + wave max
    float lmax = -1e30f;
    for (int k = l; k < d; k += 64) {
        float e = fi + f2[h * NN + jl[k]];
        e = e > 0.0f ? e : ALPHA * e;
        se[h][k] = e;
        lmax = fmaxf(lmax, e);
    }
    for (int off = 32; off; off >>= 1) lmax = fmaxf(lmax, __shfl_down(lmax, off));
    float m = __shfl(lmax, 0);
    // pass 2: exp + wave sum (same lanes wrote these k's — no cross-lane dep yet)
    float ls = 0.0f;
    for (int k = l; k < d; k += 64) {
        float p = __expf(se[h][k] - m);
        se[h][k] = p;
        ls += p;
    }
    for (int off = 32; off; off >>= 1) ls += __shfl_down(ls, off);
    float s = __shfl(ls, 0);
    __syncthreads();   // se[] now read cross-lane
    // pass 3: weighted gather of neighbor features
    float acc = 0.0f;
    for (int k = 0; k < d; ++k) {
        acc += se[h][k] * H[(size_t)jl[k] * FEAT + h * 64 + l];
    }
    float o = acc / s;
    o = o > 0.0f ? o : __expf(o) - 1.0f;   // ELU (concat=True path)
    out[(size_t)i * FEAT + h * 64 + l] = o;
}

// ---------------------------------------------------------------------------
// Layer-2 sparse attention (Fout=512, no ELU). Block = 256 threads per node.
__global__ __launch_bounds__(256) void att2_kernel(
    const float* __restrict__ H, const float* __restrict__ f1,
    const float* __restrict__ f2, const int* __restrict__ deg,
    const int* __restrict__ cols, float* __restrict__ out) {
    int i = blockIdx.x;
    int t = threadIdx.x;
    __shared__ int jl[MAXDEG];
    __shared__ float sp[MAXDEG];
    __shared__ float red[4];
    __shared__ int sdeg;
    if (t == 0) sdeg = deg[i];
    __syncthreads();
    int d = sdeg;
    if (t < d) jl[t] = cols[i * MAXDEG + t];
    __syncthreads();
    float e = 0.0f, lmax = -1e30f;
    if (t < d) {
        e = f1[i] + f2[jl[t]];
        e = e > 0.0f ? e : ALPHA * e;
        lmax = e;
    }
    for (int off = 32; off; off >>= 1) lmax = fmaxf(lmax, __shfl_down(lmax, off));
    if ((t & 63) == 0) red[t >> 6] = lmax;
    __syncthreads();
    float m = fmaxf(fmaxf(red[0], red[1]), fmaxf(red[2], red[3]));
    float p = 0.0f;
    if (t < d) { p = __expf(e - m); sp[t] = p; }
    float ls = p;
    for (int off = 32; off; off >>= 1) ls += __shfl_down(ls, off);
    __syncthreads();                       // red[] reads done before overwrite
    if ((t & 63) == 0) red[t >> 6] = ls;
    __syncthreads();                       // also publishes sp[]
    float s = red[0] + red[1] + red[2] + red[3];
    float inv = 1.0f / s;
    float acc0 = 0.0f, acc1 = 0.0f;
    for (int k = 0; k < d; ++k) {
        float pk = sp[k];
        const float* hr = H + (size_t)jl[k] * FEAT;
        acc0 += pk * hr[t];
        acc1 += pk * hr[t + 256];
    }
    out[(size_t)i * FEAT + t]       = acc0 * inv;
    out[(size_t)i * FEAT + t + 256] = acc1 * inv;
}

// ---------------------------------------------------------------------------
// logits = elu(X @ lin_W + b); out = log_softmax(logits). One block/row.
__global__ __launch_bounds__(64) void final_kernel(
    const float* __restrict__ X, const float* __restrict__ linW,
    const float* __restrict__ linb, float* __restrict__ out) {
    int i = blockIdx.x;
    int t = threadIdx.x;
    __shared__ float sx[FEAT];
    __shared__ float sl[NCLS];
    for (int f = t; f < FEAT; f += 64) sx[f] = X[(size_t)i * FEAT + f];
    __syncthreads();
    if (t < NCLS) {
        float acc = linb[t];
        for (int f = 0; f < FEAT; ++f) acc += sx[f] * linW[f * NCLS + t];
        acc = acc > 0.0f ? acc : __expf(acc) - 1.0f;
        sl[t] = acc;
    }
    __syncthreads();
    if (t < NCLS) {
        float m = sl[0];
        for (int c = 1; c < NCLS; ++c) m = fmaxf(m, sl[c]);
        float ssum = 0.0f;
        for (int c = 0; c < NCLS; ++c) ssum += __expf(sl[c] - m);
        out[i * NCLS + t] = sl[t] - m - logf(ssum);
    }
}

// ---------------------------------------------------------------------------
extern "C" void kernel_launch(void* const* d_in, const int* in_sizes, int n_in,
                              void* d_out, int out_size, void* d_ws, size_t ws_size,
                              hipStream_t stream) {
    const float* x        = (const float*)d_in[0];
    const float* rel      = (const float*)d_in[1];
    // d_in[2] rel_dict: unused (non-math constant per reference)
    const float* adj      = (const float*)d_in[3];
    const float* adj_ad   = (const float*)d_in[4];
    const float* W_heads  = (const float*)d_in[5];
    const float* a1_heads = (const float*)d_in[6];
    const float* a2_heads = (const float*)d_in[7];
    const float* W_out    = (const float*)d_in[8];
    const float* a1_out   = (const float*)d_in[9];
    const float* a2_out   = (const float*)d_in[10];
    const float* lin_W    = (const float*)d_in[11];
    const float* lin_b    = (const float*)d_in[12];
    float* out = (float*)d_out;

    char* ws = (char*)d_ws;
    float* A    = (float*)(ws);                                   // 8 MB  [4096,512]
    float* B    = (float*)(ws + (8u  << 20));                     // 8 MB  [4096,512]
    float* D    = (float*)(ws + (16u << 20));                     // 8 MB  [4096,512]
    float* Wcat = (float*)(ws + (24u << 20));                     // 1 MB  [512,512]
    float* f1   = (float*)(ws + (25u << 20));                     // 128 KB [8,4096]
    float* f2   = (float*)(ws + (25u << 20) + (128u << 10));      // 128 KB
    float* f1o  = (float*)(ws + (25u << 20) + (256u << 10));      // 16 KB
    float* f2o  = (float*)(ws + (25u << 20) + (272u << 10));      // 16 KB
    int*   deg  = (int*)  (ws + (25u << 20) + (288u << 10));      // 16 KB
    int*   cols = (int*)  (ws + (26u << 20));                     // 2 MB  [4096,128]

    // adjacency -> capped CSR (only reader of the 64 MB adj)
    csr_kernel<<<NN, 256, 0, stream>>>(adj, deg, cols);
    // xr = x + adj_ad @ rel
    relmm_add_kernel<<<NN, 128, 0, stream>>>(x, adj_ad, rel, A);
    // head-concat weight permute
    wcat_kernel<<<1024, 256, 0, stream>>>(W_heads, Wcat);
    // H1 (all heads fused) = xr @ Wcat
    sgemm_kernel<<<dim3(64, 8), 256, 0, stream>>>(A, Wcat, B);
    // per-head f1/f2
    headdot_kernel<<<dim3(NN, 2), 256, 0, stream>>>(B, a1_heads, a2_heads, f1, f2);
    // layer-1 sparse attention + ELU -> hcat
    att1_kernel<<<NN, 512, 0, stream>>>(B, f1, f2, deg, cols, D);
    // xr2 = hcat + adj_ad @ rel
    relmm_add_kernel<<<NN, 128, 0, stream>>>(D, adj_ad, rel, A);
    // h2 = xr2 @ W_out
    sgemm_kernel<<<dim3(64, 8), 256, 0, stream>>>(A, W_out, B);
    // f1o/f2o
    rowdot_kernel<<<NN, 256, 0, stream>>>(B, a1_out, a2_out, f1o, f2o);
    // layer-2 sparse attention -> out2
    att2_kernel<<<NN, 256, 0, stream>>>(B, f1o, f2o, deg, cols, D);
    // classifier + log_softmax
    final_kernel<<<NN, 64, 0, stream>>>(D, lin_W, lin_b, out);
}

// Round 3
// 292.687 us; speedup vs baseline: 1.1845x; 1.1845x over previous
//
#include <hip/hip_runtime.h>

#define NN      4096
#define FEAT    512
#define NHID    64
#define NHEADS  8
#define NCLS    16
#define MAXDEG  128
#define ALPHA   0.2f

typedef __bf16 bf16_t;
typedef __bf16 bf16x8_t __attribute__((ext_vector_type(8)));
typedef float  f32x4_t  __attribute__((ext_vector_type(4)));

__device__ inline unsigned short f2bf(float f) {
    unsigned int u = __float_as_uint(f);
    u += 0x7fffu + ((u >> 16) & 1u);          // round-to-nearest-even
    return (unsigned short)(u >> 16);
}

// ---------------------------------------------------------------------------
// out_bf[i,:] = bf16( in[i,:] + adj_ad[i,:] @ rel )   ([N,64]@[64,512])
// block = 128 threads, one row per block, each thread owns 4 features.
__global__ __launch_bounds__(128) void relmm_add_bf16_kernel(
    const float* __restrict__ in, const float* __restrict__ adj_ad,
    const float* __restrict__ rel, bf16_t* __restrict__ out) {
    int i = blockIdx.x;
    int t = threadIdx.x;            // 0..127
    __shared__ float sa[64];
    if (t < 64) sa[t] = adj_ad[i * 64 + t];
    __syncthreads();
    float4 acc = ((const float4*)(in + (size_t)i * FEAT))[t];
    for (int r = 0; r < 64; ++r) {
        float a = sa[r];
        float4 rv = ((const float4*)(rel + r * FEAT))[t];
        acc.x += a * rv.x; acc.y += a * rv.y;
        acc.z += a * rv.z; acc.w += a * rv.w;
    }
    ushort4 o;
    o.x = f2bf(acc.x); o.y = f2bf(acc.y); o.z = f2bf(acc.z); o.w = f2bf(acc.w);
    *(ushort4*)(out + (size_t)i * FEAT + 4 * t) = o;
}

// ---------------------------------------------------------------------------
// WcatT[n][k] = bf16(W_heads[h=n>>6][k][f=n&63])  (transposed, head-concat)
__global__ __launch_bounds__(256) void wcatT_kernel(
    const float* __restrict__ Wh, unsigned short* __restrict__ WT) {
    int idx = blockIdx.x * 256 + threadIdx.x;     // 0 .. 262143
    int n = idx >> 9;
    int k = idx & 511;
    int h = n >> 6;
    int f = n & 63;
    WT[idx] = f2bf(Wh[(h * 512 + k) * 64 + f]);
}

// ---------------------------------------------------------------------------
// WoT[n][k] = bf16(W_out[k][n])   (transposed cast, 512x512)
__global__ __launch_bounds__(256) void woutT_kernel(
    const float* __restrict__ W, unsigned short* __restrict__ WT) {
    int idx = blockIdx.x * 256 + threadIdx.x;     // 0 .. 262143
    int n = idx >> 9;
    int k = idx & 511;
    WT[idx] = f2bf(W[k * 512 + n]);
}

// ---------------------------------------------------------------------------
// C[4096,512] fp32 = A[4096,512] bf16 @ Bt^T, Bt[n][k] bf16 (512x512).
// 64x64 tile / block, BK=64, 256 threads (4 waves), 16x16x32 bf16 MFMA.
// Wave w computes rows [bm+16w, bm+16w+16) x 64 cols (4 MFMA n-tiles).
__global__ __launch_bounds__(256) void gemm_bf16_kernel(
    const bf16_t* __restrict__ A, const bf16_t* __restrict__ Bt,
    float* __restrict__ C) {
    __shared__ __align__(16) bf16_t As[64][72];   // pitch 72 elems = 144 B
    __shared__ __align__(16) bf16_t Bs[64][72];
    const int bm = blockIdx.x * 64;
    const int bn = blockIdx.y * 64;
    const int t  = threadIdx.x;
    const int lr = t >> 3;            // 0..31 staging row
    const int lc = (t & 7) * 8;       // staging col (elems)
    const int l  = t & 63;
    const int w  = t >> 6;
    const int mrow = w * 16 + (l & 15);
    const int nrow = l & 15;
    const int q8 = (l >> 4) * 8;

    f32x4_t acc[4] = {};
    for (int k0 = 0; k0 < FEAT; k0 += 64) {
        *(uint4*)&As[lr][lc]      = *(const uint4*)(A  + (size_t)(bm + lr)      * FEAT + k0 + lc);
        *(uint4*)&As[32 + lr][lc] = *(const uint4*)(A  + (size_t)(bm + 32 + lr) * FEAT + k0 + lc);
        *(uint4*)&Bs[lr][lc]      = *(const uint4*)(Bt + (size_t)(bn + lr)      * FEAT + k0 + lc);
        *(uint4*)&Bs[32 + lr][lc] = *(const uint4*)(Bt + (size_t)(bn + 32 + lr) * FEAT + k0 + lc);
        __syncthreads();
        #pragma unroll
        for (int kk = 0; kk < 64; kk += 32) {
            bf16x8_t a = *(const bf16x8_t*)&As[mrow][kk + q8];
            #pragma unroll
            for (int nt = 0; nt < 4; ++nt) {
                bf16x8_t b = *(const bf16x8_t*)&Bs[nt * 16 + nrow][kk + q8];
                acc[nt] = __builtin_amdgcn_mfma_f32_16x16x32_bf16(a, b, acc[nt], 0, 0, 0);
            }
        }
        __syncthreads();
    }
    // C/D layout: col = lane&15, row = (lane>>4)*4 + reg
    const int crow = bm + w * 16 + (l >> 4) * 4;
    const int ccol = bn + (l & 15);
    #pragma unroll
    for (int nt = 0; nt < 4; ++nt)
        #pragma unroll
        for (int r = 0; r < 4; ++r)
            C[(size_t)(crow + r) * FEAT + ccol + nt * 16] = acc[nt][r];
}

// ---------------------------------------------------------------------------
// f1[h,i] = sum_f H[i, h*64+f]*a1[h,f];  f2 likewise. One wave per (i,h).
__global__ __launch_bounds__(256) void headdot_kernel(
    const float* __restrict__ H, const float* __restrict__ a1,
    const float* __restrict__ a2, float* __restrict__ f1, float* __restrict__ f2) {
    int i = blockIdx.x;
    int w = threadIdx.x >> 6;
    int l = threadIdx.x & 63;
    int h = blockIdx.y * 4 + w;
    float v = H[(size_t)i * FEAT + h * 64 + l];
    float s1 = v * a1[h * 64 + l];
    float s2 = v * a2[h * 64 + l];
    for (int off = 32; off; off >>= 1) {
        s1 += __shfl_down(s1, off);
        s2 += __shfl_down(s2, off);
    }
    if (l == 0) { f1[h * NN + i] = s1; f2[h * NN + i] = s2; }
}

// ---------------------------------------------------------------------------
// f1o[i] = H[i,:] @ a1_out; f2o likewise (F=512). One block (256 thr) per row.
__global__ __launch_bounds__(256) void rowdot_kernel(
    const float* __restrict__ H, const float* __restrict__ a1,
    const float* __restrict__ a2, float* __restrict__ f1, float* __restrict__ f2) {
    int i = blockIdx.x;
    int t = threadIdx.x;
    float v0 = H[(size_t)i * FEAT + t];
    float v1 = H[(size_t)i * FEAT + 256 + t];
    float s1 = v0 * a1[t] + v1 * a1[256 + t];
    float s2 = v0 * a2[t] + v1 * a2[256 + t];
    for (int off = 32; off; off >>= 1) {
        s1 += __shfl_down(s1, off);
        s2 += __shfl_down(s2, off);
    }
    __shared__ float r1[4], r2[4];
    if ((t & 63) == 0) { r1[t >> 6] = s1; r2[t >> 6] = s2; }
    __syncthreads();
    if (t == 0) {
        f1[i] = r1[0] + r1[1] + r1[2] + r1[3];
        f2[i] = r2[0] + r2[1] + r2[2] + r2[3];
    }
}

// ---------------------------------------------------------------------------
// CSR build (unordered cols; softmax/accum are order-independent sums).
__global__ __launch_bounds__(256) void csr_kernel(
    const float* __restrict__ adj, int* __restrict__ deg, int* __restrict__ cols) {
    int i = blockIdx.x;
    __shared__ int cnt;
    if (threadIdx.x == 0) cnt = 0;
    __syncthreads();
    const float* row = adj + (size_t)i * NN;
    for (int j = threadIdx.x; j < NN; j += 256) {
        if (row[j] > 0.0f) {
            int p = atomicAdd(&cnt, 1);
            if (p < MAXDEG) cols[i * MAXDEG + p] = j;
        }
    }
    __syncthreads();
    if (threadIdx.x == 0) deg[i] = cnt > MAXDEG ? MAXDEG : cnt;
}

// ---------------------------------------------------------------------------
// Layer-1 sparse attention + ELU. Block = 512 threads (8 waves = 8 heads),
// one node per block, lane = hidden feature.
__global__ __launch_bounds__(512) void att1_kernel(
    const float* __restrict__ H, const float* __restrict__ f1,
    const float* __restrict__ f2, const int* __restrict__ deg,
    const int* __restrict__ cols, float* __restrict__ out) {
    int i = blockIdx.x;
    int h = threadIdx.x >> 6;
    int l = threadIdx.x & 63;
    __shared__ int jl[MAXDEG];
    __shared__ float se[NHEADS][MAXDEG];
    __shared__ int sdeg;
    if (threadIdx.x == 0) sdeg = deg[i];
    __syncthreads();
    int d = sdeg;
    for (int k = threadIdx.x; k < d; k += 512) jl[k] = cols[i * MAXDEG + k];
    __syncthreads();
    float fi = f1[h * NN + i];
    float lmax = -1e30f;
    for (int k = l; k < d; k += 64) {
        float e = fi + f2[h * NN + jl[k]];
        e = e > 0.0f ? e : ALPHA * e;
        se[h][k] = e;
        lmax = fmaxf(lmax, e);
    }
    for (int off = 32; off; off >>= 1) lmax = fmaxf(lmax, __shfl_down(lmax, off));
    float m = __shfl(lmax, 0);
    float ls = 0.0f;
    for (int k = l; k < d; k += 64) {
        float p = __expf(se[h][k] - m);
        se[h][k] = p;
        ls += p;
    }
    for (int off = 32; off; off >>= 1) ls += __shfl_down(ls, off);
    float s = __shfl(ls, 0);
    __syncthreads();
    float acc = 0.0f;
    for (int k = 0; k < d; ++k) {
        acc += se[h][k] * H[(size_t)jl[k] * FEAT + h * 64 + l];
    }
    float o = acc / s;
    o = o > 0.0f ? o : __expf(o) - 1.0f;   // ELU (concat=True path)
    out[(size_t)i * FEAT + h * 64 + l] = o;
}

// ---------------------------------------------------------------------------
// Layer-2 sparse attention (Fout=512, no ELU). Block = 256 threads per node.
__global__ __launch_bounds__(256) void att2_kernel(
    const float* __restrict__ H, const float* __restrict__ f1,
    const float* __restrict__ f2, const int* __restrict__ deg,
    const int* __restrict__ cols, float* __restrict__ out) {
    int i = blockIdx.x;
    int t = threadIdx.x;
    __shared__ int jl[MAXDEG];
    __shared__ float sp[MAXDEG];
    __shared__ float red[4];
    __shared__ int sdeg;
    if (t == 0) sdeg = deg[i];
    __syncthreads();
    int d = sdeg;
    if (t < d) jl[t] = cols[i * MAXDEG + t];
    __syncthreads();
    float e = 0.0f, lmax = -1e30f;
    if (t < d) {
        e = f1[i] + f2[jl[t]];
        e = e > 0.0f ? e : ALPHA * e;
        lmax = e;
    }
    for (int off = 32; off; off >>= 1) lmax = fmaxf(lmax, __shfl_down(lmax, off));
    if ((t & 63) == 0) red[t >> 6] = lmax;
    __syncthreads();
    float m = fmaxf(fmaxf(red[0], red[1]), fmaxf(red[2], red[3]));
    float p = 0.0f;
    if (t < d) { p = __expf(e - m); sp[t] = p; }
    float ls = p;
    for (int off = 32; off; off >>= 1) ls += __shfl_down(ls, off);
    __syncthreads();
    if ((t & 63) == 0) red[t >> 6] = ls;
    __syncthreads();
    float s = red[0] + red[1] + red[2] + red[3];
    float inv = 1.0f / s;
    float acc0 = 0.0f, acc1 = 0.0f;
    for (int k = 0; k < d; ++k) {
        float pk = sp[k];
        const float* hr = H + (size_t)jl[k] * FEAT;
        acc0 += pk * hr[t];
        acc1 += pk * hr[t + 256];
    }
    out[(size_t)i * FEAT + t]       = acc0 * inv;
    out[(size_t)i * FEAT + t + 256] = acc1 * inv;
}

// ---------------------------------------------------------------------------
// logits = elu(X @ lin_W + b); out = log_softmax(logits). One block/row.
__global__ __launch_bounds__(64) void final_kernel(
    const float* __restrict__ X, const float* __restrict__ linW,
    const float* __restrict__ linb, float* __restrict__ out) {
    int i = blockIdx.x;
    int t = threadIdx.x;
    __shared__ float sx[FEAT];
    __shared__ float sl[NCLS];
    for (int f = t; f < FEAT; f += 64) sx[f] = X[(size_t)i * FEAT + f];
    __syncthreads();
    if (t < NCLS) {
        float acc = linb[t];
        for (int f = 0; f < FEAT; ++f) acc += sx[f] * linW[f * NCLS + t];
        acc = acc > 0.0f ? acc : __expf(acc) - 1.0f;
        sl[t] = acc;
    }
    __syncthreads();
    if (t < NCLS) {
        float m = sl[0];
        for (int c = 1; c < NCLS; ++c) m = fmaxf(m, sl[c]);
        float ssum = 0.0f;
        for (int c = 0; c < NCLS; ++c) ssum += __expf(sl[c] - m);
        out[i * NCLS + t] = sl[t] - m - logf(ssum);
    }
}

// ---------------------------------------------------------------------------
extern "C" void kernel_launch(void* const* d_in, const int* in_sizes, int n_in,
                              void* d_out, int out_size, void* d_ws, size_t ws_size,
                              hipStream_t stream) {
    const float* x        = (const float*)d_in[0];
    const float* rel      = (const float*)d_in[1];
    // d_in[2] rel_dict: unused (non-math constant per reference)
    const float* adj      = (const float*)d_in[3];
    const float* adj_ad   = (const float*)d_in[4];
    const float* W_heads  = (const float*)d_in[5];
    const float* a1_heads = (const float*)d_in[6];
    const float* a2_heads = (const float*)d_in[7];
    const float* W_out    = (const float*)d_in[8];
    const float* a1_out   = (const float*)d_in[9];
    const float* a2_out   = (const float*)d_in[10];
    const float* lin_W    = (const float*)d_in[11];
    const float* lin_b    = (const float*)d_in[12];
    float* out = (float*)d_out;

    char* ws = (char*)d_ws;
    bf16_t* Abf  = (bf16_t*)(ws);                                 // 4 MB  [4096,512] bf16
    float*  Hh   = (float*) (ws + (4u  << 20));                   // 8 MB  [4096,512] fp32
    float*  D    = (float*) (ws + (12u << 20));                   // 8 MB  [4096,512] fp32
    bf16_t* WcT  = (bf16_t*)(ws + (20u << 20));                   // 0.5 MB [512,512] bf16 (transposed)
    bf16_t* WoT  = (bf16_t*)(ws + (20u << 20) + (512u << 10));    // 0.5 MB
    float*  f1   = (float*) (ws + (21u << 20));                   // 128 KB [8,4096]
    float*  f2   = (float*) (ws + (21u << 20) + (128u << 10));    // 128 KB
    float*  f1o  = (float*) (ws + (21u << 20) + (256u << 10));    // 16 KB
    float*  f2o  = (float*) (ws + (21u << 20) + (272u << 10));    // 16 KB
    int*    deg  = (int*)   (ws + (21u << 20) + (288u << 10));    // 16 KB
    int*    cols = (int*)   (ws + (22u << 20));                   // 2 MB  [4096,128]

    // adjacency -> capped CSR (only reader of the 64 MB adj)
    csr_kernel<<<NN, 256, 0, stream>>>(adj, deg, cols);
    // xr = bf16(x + adj_ad @ rel)
    relmm_add_bf16_kernel<<<NN, 128, 0, stream>>>(x, adj_ad, rel, Abf);
    // weight permute/cast (transposed bf16)
    wcatT_kernel<<<1024, 256, 0, stream>>>(W_heads, (unsigned short*)WcT);
    woutT_kernel<<<1024, 256, 0, stream>>>(W_out, (unsigned short*)WoT);
    // H1 (all heads fused) = xr @ Wcat   (bf16 MFMA, fp32 accum)
    gemm_bf16_kernel<<<dim3(64, 8), 256, 0, stream>>>(Abf, WcT, Hh);
    // per-head f1/f2
    headdot_kernel<<<dim3(NN, 2), 256, 0, stream>>>(Hh, a1_heads, a2_heads, f1, f2);
    // layer-1 sparse attention + ELU -> hcat
    att1_kernel<<<NN, 512, 0, stream>>>(Hh, f1, f2, deg, cols, D);
    // xr2 = bf16(hcat + adj_ad @ rel)
    relmm_add_bf16_kernel<<<NN, 128, 0, stream>>>(D, adj_ad, rel, Abf);
    // h2 = xr2 @ W_out
    gemm_bf16_kernel<<<dim3(64, 8), 256, 0, stream>>>(Abf, WoT, Hh);
    // f1o/f2o
    rowdot_kernel<<<NN, 256, 0, stream>>>(Hh, a1_out, a2_out, f1o, f2o);
    // layer-2 sparse attention -> out2
    att2_kernel<<<NN, 256, 0, stream>>>(Hh, f1o, f2o, deg, cols, D);
    // classifier + log_softmax
    final_kernel<<<NN, 64, 0, stream>>>(D, lin_W, lin_b, out);
}

// Round 4
// 276.169 us; speedup vs baseline: 1.2553x; 1.0598x over previous
//
#include <hip/hip_runtime.h>

#define NN      4096
#define FEAT    512
#define NHID    64
#define NHEADS  8
#define NCLS    16
#define MAXDEG  128
#define ALPHA   0.2f

typedef __bf16 bf16_t;
typedef __bf16 bf16x8_t __attribute__((ext_vector_type(8)));
typedef float  f32x4_t  __attribute__((ext_vector_type(4)));

__device__ inline unsigned short f2bf(float f) {
    unsigned int u = __float_as_uint(f);
    u += 0x7fffu + ((u >> 16) & 1u);          // round-to-nearest-even
    return (unsigned short)(u >> 16);
}

// ---------------------------------------------------------------------------
// out_bf[i,:] = bf16( in[i,:] + adj_ad[i,:] @ rel )   ([N,64]@[64,512])
__global__ __launch_bounds__(128) void relmm_add_bf16_kernel(
    const float* __restrict__ in, const float* __restrict__ adj_ad,
    const float* __restrict__ rel, bf16_t* __restrict__ out) {
    int i = blockIdx.x;
    int t = threadIdx.x;            // 0..127
    __shared__ float sa[64];
    if (t < 64) sa[t] = adj_ad[i * 64 + t];
    __syncthreads();
    float4 acc = ((const float4*)(in + (size_t)i * FEAT))[t];
    for (int r = 0; r < 64; ++r) {
        float a = sa[r];
        float4 rv = ((const float4*)(rel + r * FEAT))[t];
        acc.x += a * rv.x; acc.y += a * rv.y;
        acc.z += a * rv.z; acc.w += a * rv.w;
    }
    ushort4 o;
    o.x = f2bf(acc.x); o.y = f2bf(acc.y); o.z = f2bf(acc.z); o.w = f2bf(acc.w);
    *(ushort4*)(out + (size_t)i * FEAT + 4 * t) = o;
}

// ---------------------------------------------------------------------------
// WcatT[n][k] = bf16(W_heads[h=n>>6][k][f=n&63])  (transposed, head-concat)
__global__ __launch_bounds__(256) void wcatT_kernel(
    const float* __restrict__ Wh, unsigned short* __restrict__ WT) {
    int idx = blockIdx.x * 256 + threadIdx.x;     // 0 .. 262143
    int n = idx >> 9;
    int k = idx & 511;
    int h = n >> 6;
    int f = n & 63;
    WT[idx] = f2bf(Wh[(h * 512 + k) * 64 + f]);
}

// ---------------------------------------------------------------------------
// WoT[n][k] = bf16(W_out[k][n])   (transposed cast, 512x512)
__global__ __launch_bounds__(256) void woutT_kernel(
    const float* __restrict__ W, unsigned short* __restrict__ WT) {
    int idx = blockIdx.x * 256 + threadIdx.x;     // 0 .. 262143
    int n = idx >> 9;
    int k = idx & 511;
    WT[idx] = f2bf(W[k * 512 + n]);
}

// ---------------------------------------------------------------------------
// C[4096,512] fp32 = A[4096,512] bf16 @ Bt^T, Bt[n][k] bf16 (512x512).
// 64x64 tile / block, BK=64, 256 threads (4 waves), 16x16x32 bf16 MFMA.
__global__ __launch_bounds__(256) void gemm_bf16_kernel(
    const bf16_t* __restrict__ A, const bf16_t* __restrict__ Bt,
    float* __restrict__ C) {
    __shared__ __align__(16) bf16_t As[64][72];   // pitch 72 elems = 144 B
    __shared__ __align__(16) bf16_t Bs[64][72];
    const int bm = blockIdx.x * 64;
    const int bn = blockIdx.y * 64;
    const int t  = threadIdx.x;
    const int lr = t >> 3;            // 0..31 staging row
    const int lc = (t & 7) * 8;       // staging col (elems)
    const int l  = t & 63;
    const int w  = t >> 6;
    const int mrow = w * 16 + (l & 15);
    const int nrow = l & 15;
    const int q8 = (l >> 4) * 8;

    f32x4_t acc[4] = {};
    for (int k0 = 0; k0 < FEAT; k0 += 64) {
        *(uint4*)&As[lr][lc]      = *(const uint4*)(A  + (size_t)(bm + lr)      * FEAT + k0 + lc);
        *(uint4*)&As[32 + lr][lc] = *(const uint4*)(A  + (size_t)(bm + 32 + lr) * FEAT + k0 + lc);
        *(uint4*)&Bs[lr][lc]      = *(const uint4*)(Bt + (size_t)(bn + lr)      * FEAT + k0 + lc);
        *(uint4*)&Bs[32 + lr][lc] = *(const uint4*)(Bt + (size_t)(bn + 32 + lr) * FEAT + k0 + lc);
        __syncthreads();
        #pragma unroll
        for (int kk = 0; kk < 64; kk += 32) {
            bf16x8_t a = *(const bf16x8_t*)&As[mrow][kk + q8];
            #pragma unroll
            for (int nt = 0; nt < 4; ++nt) {
                bf16x8_t b = *(const bf16x8_t*)&Bs[nt * 16 + nrow][kk + q8];
                acc[nt] = __builtin_amdgcn_mfma_f32_16x16x32_bf16(a, b, acc[nt], 0, 0, 0);
            }
        }
        __syncthreads();
    }
    const int crow = bm + w * 16 + (l >> 4) * 4;
    const int ccol = bn + (l & 15);
    #pragma unroll
    for (int nt = 0; nt < 4; ++nt)
        #pragma unroll
        for (int r = 0; r < 4; ++r)
            C[(size_t)(crow + r) * FEAT + ccol + nt * 16] = acc[nt][r];
}

// ---------------------------------------------------------------------------
// f1[h,i] = sum_f H[i, h*64+f]*a1[h,f];  f2 likewise. One wave per (i,h).
__global__ __launch_bounds__(256) void headdot_kernel(
    const float* __restrict__ H, const float* __restrict__ a1,
    const float* __restrict__ a2, float* __restrict__ f1, float* __restrict__ f2) {
    int i = blockIdx.x;
    int w = threadIdx.x >> 6;
    int l = threadIdx.x & 63;
    int h = blockIdx.y * 4 + w;
    float v = H[(size_t)i * FEAT + h * 64 + l];
    float s1 = v * a1[h * 64 + l];
    float s2 = v * a2[h * 64 + l];
    for (int off = 32; off; off >>= 1) {
        s1 += __shfl_down(s1, off);
        s2 += __shfl_down(s2, off);
    }
    if (l == 0) { f1[h * NN + i] = s1; f2[h * NN + i] = s2; }
}

// ---------------------------------------------------------------------------
// f1o[i] = H[i,:] @ a1_out; f2o likewise (F=512). One block (256 thr) per row.
__global__ __launch_bounds__(256) void rowdot_kernel(
    const float* __restrict__ H, const float* __restrict__ a1,
    const float* __restrict__ a2, float* __restrict__ f1, float* __restrict__ f2) {
    int i = blockIdx.x;
    int t = threadIdx.x;
    float v0 = H[(size_t)i * FEAT + t];
    float v1 = H[(size_t)i * FEAT + 256 + t];
    float s1 = v0 * a1[t] + v1 * a1[256 + t];
    float s2 = v0 * a2[t] + v1 * a2[256 + t];
    for (int off = 32; off; off >>= 1) {
        s1 += __shfl_down(s1, off);
        s2 += __shfl_down(s2, off);
    }
    __shared__ float r1[4], r2[4];
    if ((t & 63) == 0) { r1[t >> 6] = s1; r2[t >> 6] = s2; }
    __syncthreads();
    if (t == 0) {
        f1[i] = r1[0] + r1[1] + r1[2] + r1[3];
        f2[i] = r2[0] + r2[1] + r2[2] + r2[3];
    }
}

// ---------------------------------------------------------------------------
// CSR build, float4 scan (unordered cols; downstream sums are order-indep).
__global__ __launch_bounds__(256) void csr_kernel(
    const float* __restrict__ adj, int* __restrict__ deg, int* __restrict__ cols) {
    int i = blockIdx.x;
    __shared__ int cnt;
    if (threadIdx.x == 0) cnt = 0;
    __syncthreads();
    const float4* row4 = (const float4*)(adj + (size_t)i * NN);
    for (int j4 = threadIdx.x; j4 < NN / 4; j4 += 256) {
        float4 v = row4[j4];
        int j = j4 * 4;
        if (v.x > 0.0f) { int p = atomicAdd(&cnt, 1); if (p < MAXDEG) cols[i * MAXDEG + p] = j; }
        if (v.y > 0.0f) { int p = atomicAdd(&cnt, 1); if (p < MAXDEG) cols[i * MAXDEG + p] = j + 1; }
        if (v.z > 0.0f) { int p = atomicAdd(&cnt, 1); if (p < MAXDEG) cols[i * MAXDEG + p] = j + 2; }
        if (v.w > 0.0f) { int p = atomicAdd(&cnt, 1); if (p < MAXDEG) cols[i * MAXDEG + p] = j + 3; }
    }
    __syncthreads();
    if (threadIdx.x == 0) deg[i] = cnt > MAXDEG ? MAXDEG : cnt;
}

// ---------------------------------------------------------------------------
// Layer-1 sparse attention + ELU. Block = 512 threads (8 waves = 8 heads),
// one node per block. Gather: 4 neighbor-slots x 16 col-groups per wave,
// float4 loads, x2 unroll -> 8 loads in flight, d/8 loop iterations.
__global__ __launch_bounds__(512) void att1_kernel(
    const float* __restrict__ H, const float* __restrict__ f1,
    const float* __restrict__ f2, const int* __restrict__ deg,
    const int* __restrict__ cols, float* __restrict__ out) {
    int i = blockIdx.x;
    int h = threadIdx.x >> 6;
    int l = threadIdx.x & 63;
    __shared__ int jl[MAXDEG];
    __shared__ float se[NHEADS][MAXDEG];
    __shared__ int sdeg;
    if (threadIdx.x == 0) sdeg = deg[i];
    __syncthreads();
    int d = sdeg;
    for (int k = threadIdx.x; k < d; k += 512) jl[k] = cols[i * MAXDEG + k];
    __syncthreads();
    float fi = f1[h * NN + i];
    // pass 1: scores + wave max
    float lmax = -1e30f;
    for (int k = l; k < d; k += 64) {
        float e = fi + f2[h * NN + jl[k]];
        e = e > 0.0f ? e : ALPHA * e;
        se[h][k] = e;
        lmax = fmaxf(lmax, e);
    }
    for (int off = 32; off; off >>= 1) lmax = fmaxf(lmax, __shfl_down(lmax, off));
    float m = __shfl(lmax, 0);
    // pass 2: exp + wave sum
    float ls = 0.0f;
    for (int k = l; k < d; k += 64) {
        float p = __expf(se[h][k] - m);
        se[h][k] = p;
        ls += p;
    }
    for (int off = 32; off; off >>= 1) ls += __shfl_down(ls, off);
    float s = __shfl(ls, 0);
    __syncthreads();   // publish se[] for cross-lane reads
    // pass 3: neighbor-parallel vectorized gather
    const int slot = l >> 4;          // 0..3
    const int cg   = l & 15;          // col group (float4)
    float4 acc = make_float4(0.f, 0.f, 0.f, 0.f);
    for (int k0 = 0; k0 < d; k0 += 8) {
        int ka = k0 + slot;
        int kb = k0 + 4 + slot;
        if (ka < d) {
            float p = se[h][ka];
            float4 v = *(const float4*)(H + (size_t)jl[ka] * FEAT + h * 64 + cg * 4);
            acc.x += p * v.x; acc.y += p * v.y; acc.z += p * v.z; acc.w += p * v.w;
        }
        if (kb < d) {
            float p = se[h][kb];
            float4 v = *(const float4*)(H + (size_t)jl[kb] * FEAT + h * 64 + cg * 4);
            acc.x += p * v.x; acc.y += p * v.y; acc.z += p * v.z; acc.w += p * v.w;
        }
    }
    // combine the 4 neighbor slots (lanes l, l^16, l^32, l^48 share cg)
    #pragma unroll
    for (int off = 16; off <= 32; off <<= 1) {
        acc.x += __shfl_xor(acc.x, off);
        acc.y += __shfl_xor(acc.y, off);
        acc.z += __shfl_xor(acc.z, off);
        acc.w += __shfl_xor(acc.w, off);
    }
    if (slot == 0) {
        float inv = 1.0f / s;
        float4 o;
        o.x = acc.x * inv; o.y = acc.y * inv; o.z = acc.z * inv; o.w = acc.w * inv;
        o.x = o.x > 0.0f ? o.x : __expf(o.x) - 1.0f;
        o.y = o.y > 0.0f ? o.y : __expf(o.y) - 1.0f;
        o.z = o.z > 0.0f ? o.z : __expf(o.z) - 1.0f;
        o.w = o.w > 0.0f ? o.w : __expf(o.w) - 1.0f;
        *(float4*)(out + (size_t)i * FEAT + h * 64 + cg * 4) = o;
    }
}

// ---------------------------------------------------------------------------
// Layer-2 sparse attention (Fout=512, no ELU). Block = 256 threads per node.
// Gather: 2 neighbor-slots x 128 col-groups, float4, x2 unroll.
__global__ __launch_bounds__(256) void att2_kernel(
    const float* __restrict__ H, const float* __restrict__ f1,
    const float* __restrict__ f2, const int* __restrict__ deg,
    const int* __restrict__ cols, float* __restrict__ out) {
    int i = blockIdx.x;
    int t = threadIdx.x;
    __shared__ int jl[MAXDEG];
    __shared__ float sp[MAXDEG];
    __shared__ float red[4];
    __shared__ float red2[FEAT];
    __shared__ int sdeg;
    if (t == 0) sdeg = deg[i];
    __syncthreads();
    int d = sdeg;
    if (t < d) jl[t] = cols[i * MAXDEG + t];
    __syncthreads();
    float e = 0.0f, lmax = -1e30f;
    if (t < d) {
        e = f1[i] + f2[jl[t]];
        e = e > 0.0f ? e : ALPHA * e;
        lmax = e;
    }
    for (int off = 32; off; off >>= 1) lmax = fmaxf(lmax, __shfl_down(lmax, off));
    if ((t & 63) == 0) red[t >> 6] = lmax;
    __syncthreads();
    float m = fmaxf(fmaxf(red[0], red[1]), fmaxf(red[2], red[3]));
    float p = 0.0f;
    if (t < d) { p = __expf(e - m); sp[t] = p; }
    float ls = p;
    for (int off = 32; off; off >>= 1) ls += __shfl_down(ls, off);
    __syncthreads();                       // red[] reads done before overwrite
    if ((t & 63) == 0) red[t >> 6] = ls;
    __syncthreads();                       // also publishes sp[]
    float s = red[0] + red[1] + red[2] + red[3];
    float inv = 1.0f / s;
    // neighbor-parallel vectorized gather
    const int slot = t >> 7;          // 0..1
    const int cg   = t & 127;         // col group (float4)
    float4 acc = make_float4(0.f, 0.f, 0.f, 0.f);
    for (int k0 = 0; k0 < d; k0 += 4) {
        int ka = k0 + slot;
        int kb = k0 + 2 + slot;
        if (ka < d) {
            float pk = sp[ka];
            float4 v = *(const float4*)(H + (size_t)jl[ka] * FEAT + cg * 4);
            acc.x += pk * v.x; acc.y += pk * v.y; acc.z += pk * v.z; acc.w += pk * v.w;
        }
        if (kb < d) {
            float pk = sp[kb];
            float4 v = *(const float4*)(H + (size_t)jl[kb] * FEAT + cg * 4);
            acc.x += pk * v.x; acc.y += pk * v.y; acc.z += pk * v.z; acc.w += pk * v.w;
        }
    }
    // combine slot 1 into slot 0 via LDS
    if (slot == 1) *(float4*)&red2[cg * 4] = acc;
    __syncthreads();
    if (slot == 0) {
        float4 b = *(const float4*)&red2[cg * 4];
        float4 o;
        o.x = (acc.x + b.x) * inv;
        o.y = (acc.y + b.y) * inv;
        o.z = (acc.z + b.z) * inv;
        o.w = (acc.w + b.w) * inv;
        *(float4*)(out + (size_t)i * FEAT + cg * 4) = o;
    }
}

// ---------------------------------------------------------------------------
// logits = elu(X @ lin_W + b); out = log_softmax(logits). One block/row.
__global__ __launch_bounds__(64) void final_kernel(
    const float* __restrict__ X, const float* __restrict__ linW,
    const float* __restrict__ linb, float* __restrict__ out) {
    int i = blockIdx.x;
    int t = threadIdx.x;
    __shared__ float sx[FEAT];
    __shared__ float sl[NCLS];
    for (int f = t; f < FEAT; f += 64) sx[f] = X[(size_t)i * FEAT + f];
    __syncthreads();
    if (t < NCLS) {
        float acc = linb[t];
        for (int f = 0; f < FEAT; ++f) acc += sx[f] * linW[f * NCLS + t];
        acc = acc > 0.0f ? acc : __expf(acc) - 1.0f;
        sl[t] = acc;
    }
    __syncthreads();
    if (t < NCLS) {
        float m = sl[0];
        for (int c = 1; c < NCLS; ++c) m = fmaxf(m, sl[c]);
        float ssum = 0.0f;
        for (int c = 0; c < NCLS; ++c) ssum += __expf(sl[c] - m);
        out[i * NCLS + t] = sl[t] - m - logf(ssum);
    }
}

// ---------------------------------------------------------------------------
extern "C" void kernel_launch(void* const* d_in, const int* in_sizes, int n_in,
                              void* d_out, int out_size, void* d_ws, size_t ws_size,
                              hipStream_t stream) {
    const float* x        = (const float*)d_in[0];
    const float* rel      = (const float*)d_in[1];
    // d_in[2] rel_dict: unused (non-math constant per reference)
    const float* adj      = (const float*)d_in[3];
    const float* adj_ad   = (const float*)d_in[4];
    const float* W_heads  = (const float*)d_in[5];
    const float* a1_heads = (const float*)d_in[6];
    const float* a2_heads = (const float*)d_in[7];
    const float* W_out    = (const float*)d_in[8];
    const float* a1_out   = (const float*)d_in[9];
    const float* a2_out   = (const float*)d_in[10];
    const float* lin_W    = (const float*)d_in[11];
    const float* lin_b    = (const float*)d_in[12];
    float* out = (float*)d_out;

    char* ws = (char*)d_ws;
    bf16_t* Abf  = (bf16_t*)(ws);                                 // 4 MB  [4096,512] bf16
    float*  Hh   = (float*) (ws + (4u  << 20));                   // 8 MB  [4096,512] fp32
    float*  D    = (float*) (ws + (12u << 20));                   // 8 MB  [4096,512] fp32
    bf16_t* WcT  = (bf16_t*)(ws + (20u << 20));                   // 0.5 MB [512,512] bf16 (transposed)
    bf16_t* WoT  = (bf16_t*)(ws + (20u << 20) + (512u << 10));    // 0.5 MB
    float*  f1   = (float*) (ws + (21u << 20));                   // 128 KB [8,4096]
    float*  f2   = (float*) (ws + (21u << 20) + (128u << 10));    // 128 KB
    float*  f1o  = (float*) (ws + (21u << 20) + (256u << 10));    // 16 KB
    float*  f2o  = (float*) (ws + (21u << 20) + (272u << 10));    // 16 KB
    int*    deg  = (int*)   (ws + (21u << 20) + (288u << 10));    // 16 KB
    int*    cols = (int*)   (ws + (22u << 20));                   // 2 MB  [4096,128]

    // adjacency -> capped CSR (only reader of the 64 MB adj)
    csr_kernel<<<NN, 256, 0, stream>>>(adj, deg, cols);
    // xr = bf16(x + adj_ad @ rel)
    relmm_add_bf16_kernel<<<NN, 128, 0, stream>>>(x, adj_ad, rel, Abf);
    // weight permute/cast (transposed bf16)
    wcatT_kernel<<<1024, 256, 0, stream>>>(W_heads, (unsigned short*)WcT);
    woutT_kernel<<<1024, 256, 0, stream>>>(W_out, (unsigned short*)WoT);
    // H1 (all heads fused) = xr @ Wcat   (bf16 MFMA, fp32 accum)
    gemm_bf16_kernel<<<dim3(64, 8), 256, 0, stream>>>(Abf, WcT, Hh);
    // per-head f1/f2
    headdot_kernel<<<dim3(NN, 2), 256, 0, stream>>>(Hh, a1_heads, a2_heads, f1, f2);
    // layer-1 sparse attention + ELU -> hcat
    att1_kernel<<<NN, 512, 0, stream>>>(Hh, f1, f2, deg, cols, D);
    // xr2 = bf16(hcat + adj_ad @ rel)
    relmm_add_bf16_kernel<<<NN, 128, 0, stream>>>(D, adj_ad, rel, Abf);
    // h2 = xr2 @ W_out
    gemm_bf16_kernel<<<dim3(64, 8), 256, 0, stream>>>(Abf, WoT, Hh);
    // f1o/f2o
    rowdot_kernel<<<NN, 256, 0, stream>>>(Hh, a1_out, a2_out, f1o, f2o);
    // layer-2 sparse attention -> out2
    att2_kernel<<<NN, 256, 0, stream>>>(Hh, f1o, f2o, deg, cols, D);
    // classifier + log_softmax
    final_kernel<<<NN, 64, 0, stream>>>(D, lin_W, lin_b, out);
}

// Round 5
// 260.490 us; speedup vs baseline: 1.3309x; 1.0602x over previous
//
#include <hip/hip_runtime.h>

#define NN      4096
#define FEAT    512
#define NHID    64
#define NHEADS  8
#define NCLS    16
#define MAXDEG  128
#define ALPHA   0.2f

typedef __bf16 bf16_t;
typedef __bf16 bf16x8_t __attribute__((ext_vector_type(8)));
typedef float  f32x4_t  __attribute__((ext_vector_type(4)));
typedef unsigned short us8_t __attribute__((ext_vector_type(8)));

__device__ inline unsigned short f2bf(float f) {
    unsigned int u = __float_as_uint(f);
    u += 0x7fffu + ((u >> 16) & 1u);          // round-to-nearest-even
    return (unsigned short)(u >> 16);
}
__device__ inline float bfu2f(unsigned short b) {
    return __uint_as_float(((unsigned int)b) << 16);
}

// ---------------------------------------------------------------------------
// out_bf[i,:] = bf16( in[i,:] + adj_ad[i,:] @ rel )   ([N,64]@[64,512])
__global__ __launch_bounds__(128) void relmm_add_bf16_kernel(
    const float* __restrict__ in, const float* __restrict__ adj_ad,
    const float* __restrict__ rel, bf16_t* __restrict__ out) {
    int i = blockIdx.x;
    int t = threadIdx.x;            // 0..127
    __shared__ float sa[64];
    if (t < 64) sa[t] = adj_ad[i * 64 + t];
    __syncthreads();
    float4 acc = ((const float4*)(in + (size_t)i * FEAT))[t];
    for (int r = 0; r < 64; ++r) {
        float a = sa[r];
        float4 rv = ((const float4*)(rel + r * FEAT))[t];
        acc.x += a * rv.x; acc.y += a * rv.y;
        acc.z += a * rv.z; acc.w += a * rv.w;
    }
    ushort4 o;
    o.x = f2bf(acc.x); o.y = f2bf(acc.y); o.z = f2bf(acc.z); o.w = f2bf(acc.w);
    *(ushort4*)(out + (size_t)i * FEAT + 4 * t) = o;
}

// ---------------------------------------------------------------------------
// WcatT[n][k] = bf16(W_heads[h=n>>6][k][f=n&63])  (transposed, head-concat)
__global__ __launch_bounds__(256) void wcatT_kernel(
    const float* __restrict__ Wh, unsigned short* __restrict__ WT) {
    int idx = blockIdx.x * 256 + threadIdx.x;     // 0 .. 262143
    int n = idx >> 9;
    int k = idx & 511;
    int h = n >> 6;
    int f = n & 63;
    WT[idx] = f2bf(Wh[(h * 512 + k) * 64 + f]);
}

// ---------------------------------------------------------------------------
// WoT[n][k] = bf16(W_out[k][n])   (transposed cast, 512x512)
__global__ __launch_bounds__(256) void woutT_kernel(
    const float* __restrict__ W, unsigned short* __restrict__ WT) {
    int idx = blockIdx.x * 256 + threadIdx.x;     // 0 .. 262143
    int n = idx >> 9;
    int k = idx & 511;
    WT[idx] = f2bf(W[k * 512 + n]);
}

// ---------------------------------------------------------------------------
// C[4096,512] fp32 (+bf16 copy) = A[4096,512] bf16 @ Bt^T, Bt[n][k] bf16.
// 64x64 tile / block, BK=64, 256 threads (4 waves), 16x16x32 bf16 MFMA.
__global__ __launch_bounds__(256) void gemm_bf16_kernel(
    const bf16_t* __restrict__ A, const bf16_t* __restrict__ Bt,
    float* __restrict__ C, unsigned short* __restrict__ Cbf) {
    __shared__ __align__(16) bf16_t As[64][72];   // pitch 72 elems = 144 B
    __shared__ __align__(16) bf16_t Bs[64][72];
    const int bm = blockIdx.x * 64;
    const int bn = blockIdx.y * 64;
    const int t  = threadIdx.x;
    const int lr = t >> 3;            // 0..31 staging row
    const int lc = (t & 7) * 8;       // staging col (elems)
    const int l  = t & 63;
    const int w  = t >> 6;
    const int mrow = w * 16 + (l & 15);
    const int nrow = l & 15;
    const int q8 = (l >> 4) * 8;

    f32x4_t acc[4] = {};
    for (int k0 = 0; k0 < FEAT; k0 += 64) {
        *(uint4*)&As[lr][lc]      = *(const uint4*)(A  + (size_t)(bm + lr)      * FEAT + k0 + lc);
        *(uint4*)&As[32 + lr][lc] = *(const uint4*)(A  + (size_t)(bm + 32 + lr) * FEAT + k0 + lc);
        *(uint4*)&Bs[lr][lc]      = *(const uint4*)(Bt + (size_t)(bn + lr)      * FEAT + k0 + lc);
        *(uint4*)&Bs[32 + lr][lc] = *(const uint4*)(Bt + (size_t)(bn + 32 + lr) * FEAT + k0 + lc);
        __syncthreads();
        #pragma unroll
        for (int kk = 0; kk < 64; kk += 32) {
            bf16x8_t a = *(const bf16x8_t*)&As[mrow][kk + q8];
            #pragma unroll
            for (int nt = 0; nt < 4; ++nt) {
                bf16x8_t b = *(const bf16x8_t*)&Bs[nt * 16 + nrow][kk + q8];
                acc[nt] = __builtin_amdgcn_mfma_f32_16x16x32_bf16(a, b, acc[nt], 0, 0, 0);
            }
        }
        __syncthreads();
    }
    const int crow = bm + w * 16 + (l >> 4) * 4;
    const int ccol = bn + (l & 15);
    #pragma unroll
    for (int nt = 0; nt < 4; ++nt)
        #pragma unroll
        for (int r = 0; r < 4; ++r) {
            float v = acc[nt][r];
            size_t off = (size_t)(crow + r) * FEAT + ccol + nt * 16;
            C[off]   = v;
            Cbf[off] = f2bf(v);
        }
}

// ---------------------------------------------------------------------------
// f1[h,i] = sum_f H[i, h*64+f]*a1[h,f];  f2 likewise. One wave per (i,h).
__global__ __launch_bounds__(256) void headdot_kernel(
    const float* __restrict__ H, const float* __restrict__ a1,
    const float* __restrict__ a2, float* __restrict__ f1, float* __restrict__ f2) {
    int i = blockIdx.x;
    int w = threadIdx.x >> 6;
    int l = threadIdx.x & 63;
    int h = blockIdx.y * 4 + w;
    float v = H[(size_t)i * FEAT + h * 64 + l];
    float s1 = v * a1[h * 64 + l];
    float s2 = v * a2[h * 64 + l];
    for (int off = 32; off; off >>= 1) {
        s1 += __shfl_down(s1, off);
        s2 += __shfl_down(s2, off);
    }
    if (l == 0) { f1[h * NN + i] = s1; f2[h * NN + i] = s2; }
}

// ---------------------------------------------------------------------------
// f1o[i] = H[i,:] @ a1_out; f2o likewise (F=512). One block (256 thr) per row.
__global__ __launch_bounds__(256) void rowdot_kernel(
    const float* __restrict__ H, const float* __restrict__ a1,
    const float* __restrict__ a2, float* __restrict__ f1, float* __restrict__ f2) {
    int i = blockIdx.x;
    int t = threadIdx.x;
    float v0 = H[(size_t)i * FEAT + t];
    float v1 = H[(size_t)i * FEAT + 256 + t];
    float s1 = v0 * a1[t] + v1 * a1[256 + t];
    float s2 = v0 * a2[t] + v1 * a2[256 + t];
    for (int off = 32; off; off >>= 1) {
        s1 += __shfl_down(s1, off);
        s2 += __shfl_down(s2, off);
    }
    __shared__ float r1[4], r2[4];
    if ((t & 63) == 0) { r1[t >> 6] = s1; r2[t >> 6] = s2; }
    __syncthreads();
    if (t == 0) {
        f1[i] = r1[0] + r1[1] + r1[2] + r1[3];
        f2[i] = r2[0] + r2[1] + r2[2] + r2[3];
    }
}

// ---------------------------------------------------------------------------
// CSR build, float4 scan (unordered cols; downstream sums are order-indep).
__global__ __launch_bounds__(256) void csr_kernel(
    const float* __restrict__ adj, int* __restrict__ deg, int* __restrict__ cols) {
    int i = blockIdx.x;
    __shared__ int cnt;
    if (threadIdx.x == 0) cnt = 0;
    __syncthreads();
    const float4* row4 = (const float4*)(adj + (size_t)i * NN);
    for (int j4 = threadIdx.x; j4 < NN / 4; j4 += 256) {
        float4 v = row4[j4];
        int j = j4 * 4;
        if (v.x > 0.0f) { int p = atomicAdd(&cnt, 1); if (p < MAXDEG) cols[i * MAXDEG + p] = j; }
        if (v.y > 0.0f) { int p = atomicAdd(&cnt, 1); if (p < MAXDEG) cols[i * MAXDEG + p] = j + 1; }
        if (v.z > 0.0f) { int p = atomicAdd(&cnt, 1); if (p < MAXDEG) cols[i * MAXDEG + p] = j + 2; }
        if (v.w > 0.0f) { int p = atomicAdd(&cnt, 1); if (p < MAXDEG) cols[i * MAXDEG + p] = j + 3; }
    }
    __syncthreads();
    if (threadIdx.x == 0) deg[i] = cnt > MAXDEG ? MAXDEG : cnt;
}

// ---------------------------------------------------------------------------
// Layer-1 sparse attention + ELU, bf16 gather. Block = 512 (8 waves = heads).
// Gather: 8 neighbor-slots x 8 col-groups (bf16x8 = 16 B), x2 unroll.
__global__ __launch_bounds__(512) void att1_kernel(
    const bf16_t* __restrict__ Hbf, const float* __restrict__ f1,
    const float* __restrict__ f2, const int* __restrict__ deg,
    const int* __restrict__ cols, float* __restrict__ out) {
    int i = blockIdx.x;
    int h = threadIdx.x >> 6;
    int l = threadIdx.x & 63;
    __shared__ int jl[MAXDEG];
    __shared__ float se[NHEADS][MAXDEG];
    __shared__ int sdeg;
    if (threadIdx.x == 0) sdeg = deg[i];
    __syncthreads();
    int d = sdeg;
    for (int k = threadIdx.x; k < d; k += 512) jl[k] = cols[i * MAXDEG + k];
    __syncthreads();
    float fi = f1[h * NN + i];
    // pass 1: scores + wave max
    float lmax = -1e30f;
    for (int k = l; k < d; k += 64) {
        float e = fi + f2[h * NN + jl[k]];
        e = e > 0.0f ? e : ALPHA * e;
        se[h][k] = e;
        lmax = fmaxf(lmax, e);
    }
    for (int off = 32; off; off >>= 1) lmax = fmaxf(lmax, __shfl_down(lmax, off));
    float m = __shfl(lmax, 0);
    // pass 2: exp + wave sum
    float ls = 0.0f;
    for (int k = l; k < d; k += 64) {
        float p = __expf(se[h][k] - m);
        se[h][k] = p;
        ls += p;
    }
    for (int off = 32; off; off >>= 1) ls += __shfl_down(ls, off);
    float s = __shfl(ls, 0);
    __syncthreads();   // publish se[] for cross-lane reads
    // pass 3: neighbor-parallel bf16 gather
    const int slot = l >> 3;          // 0..7
    const int cg   = l & 7;           // col group (8 bf16 = 16 B)
    float acc[8] = {};
    for (int k0 = 0; k0 < d; k0 += 16) {
        int ka = k0 + slot;
        int kb = k0 + 8 + slot;
        if (ka < d) {
            float p = se[h][ka];
            us8_t v = *(const us8_t*)(Hbf + (size_t)jl[ka] * FEAT + h * 64 + cg * 8);
            #pragma unroll
            for (int j = 0; j < 8; ++j) acc[j] += p * bfu2f(v[j]);
        }
        if (kb < d) {
            float p = se[h][kb];
            us8_t v = *(const us8_t*)(Hbf + (size_t)jl[kb] * FEAT + h * 64 + cg * 8);
            #pragma unroll
            for (int j = 0; j < 8; ++j) acc[j] += p * bfu2f(v[j]);
        }
    }
    // combine the 8 neighbor slots (lanes sharing cg differ in bits 3..5)
    #pragma unroll
    for (int off = 8; off <= 32; off <<= 1)
        #pragma unroll
        for (int j = 0; j < 8; ++j) acc[j] += __shfl_xor(acc[j], off);
    if (slot == 0) {
        float inv = 1.0f / s;
        float o[8];
        #pragma unroll
        for (int j = 0; j < 8; ++j) {
            float v = acc[j] * inv;
            o[j] = v > 0.0f ? v : __expf(v) - 1.0f;    // ELU
        }
        float* dst = out + (size_t)i * FEAT + h * 64 + cg * 8;
        *(float4*)(dst)     = make_float4(o[0], o[1], o[2], o[3]);
        *(float4*)(dst + 4) = make_float4(o[4], o[5], o[6], o[7]);
    }
}

// ---------------------------------------------------------------------------
// Layer-2 sparse attention, bf16 gather (Fout=512, no ELU). Block = 256.
// Gather: 4 neighbor-slots (waves) x 64 col-groups (bf16x8), x2 unroll.
__global__ __launch_bounds__(256) void att2_kernel(
    const bf16_t* __restrict__ Hbf, const float* __restrict__ f1,
    const float* __restrict__ f2, const int* __restrict__ deg,
    const int* __restrict__ cols, float* __restrict__ out) {
    int i = blockIdx.x;
    int t = threadIdx.x;
    __shared__ int jl[MAXDEG];
    __shared__ float sp[MAXDEG];
    __shared__ float red[4];
    __shared__ float part[3][FEAT];
    __shared__ int sdeg;
    if (t == 0) sdeg = deg[i];
    __syncthreads();
    int d = sdeg;
    if (t < d) jl[t] = cols[i * MAXDEG + t];
    __syncthreads();
    float e = 0.0f, lmax = -1e30f;
    if (t < d) {
        e = f1[i] + f2[jl[t]];
        e = e > 0.0f ? e : ALPHA * e;
        lmax = e;
    }
    for (int off = 32; off; off >>= 1) lmax = fmaxf(lmax, __shfl_down(lmax, off));
    if ((t & 63) == 0) red[t >> 6] = lmax;
    __syncthreads();
    float m = fmaxf(fmaxf(red[0], red[1]), fmaxf(red[2], red[3]));
    float p = 0.0f;
    if (t < d) { p = __expf(e - m); sp[t] = p; }
    float ls = p;
    for (int off = 32; off; off >>= 1) ls += __shfl_down(ls, off);
    __syncthreads();                       // red[] reads done before overwrite
    if ((t & 63) == 0) red[t >> 6] = ls;
    __syncthreads();                       // also publishes sp[]
    float s = red[0] + red[1] + red[2] + red[3];
    float inv = 1.0f / s;
    // neighbor-parallel bf16 gather
    const int slot = t >> 6;          // 0..3 (wave id)
    const int cg   = t & 63;          // col group (8 bf16)
    float acc[8] = {};
    for (int k0 = 0; k0 < d; k0 += 8) {
        int ka = k0 + slot;
        int kb = k0 + 4 + slot;
        if (ka < d) {
            float pk = sp[ka];
            us8_t v = *(const us8_t*)(Hbf + (size_t)jl[ka] * FEAT + cg * 8);
            #pragma unroll
            for (int j = 0; j < 8; ++j) acc[j] += pk * bfu2f(v[j]);
        }
        if (kb < d) {
            float pk = sp[kb];
            us8_t v = *(const us8_t*)(Hbf + (size_t)jl[kb] * FEAT + cg * 8);
            #pragma unroll
            for (int j = 0; j < 8; ++j) acc[j] += pk * bfu2f(v[j]);
        }
    }
    // combine slots 1..3 into slot 0 via LDS
    if (slot > 0) {
        float* dst = &part[slot - 1][cg * 8];
        *(float4*)(dst)     = make_float4(acc[0], acc[1], acc[2], acc[3]);
        *(float4*)(dst + 4) = make_float4(acc[4], acc[5], acc[6], acc[7]);
    }
    __syncthreads();
    if (slot == 0) {
        #pragma unroll
        for (int sl = 0; sl < 3; ++sl)
            #pragma unroll
            for (int j = 0; j < 8; ++j) acc[j] += part[sl][cg * 8 + j];
        float* dst = out + (size_t)i * FEAT + cg * 8;
        *(float4*)(dst)     = make_float4(acc[0] * inv, acc[1] * inv, acc[2] * inv, acc[3] * inv);
        *(float4*)(dst + 4) = make_float4(acc[4] * inv, acc[5] * inv, acc[6] * inv, acc[7] * inv);
    }
}

// ---------------------------------------------------------------------------
// logits = elu(X @ lin_W + b); out = log_softmax(logits). One block/row.
__global__ __launch_bounds__(64) void final_kernel(
    const float* __restrict__ X, const float* __restrict__ linW,
    const float* __restrict__ linb, float* __restrict__ out) {
    int i = blockIdx.x;
    int t = threadIdx.x;
    __shared__ float sx[FEAT];
    __shared__ float sl[NCLS];
    for (int f = t; f < FEAT; f += 64) sx[f] = X[(size_t)i * FEAT + f];
    __syncthreads();
    if (t < NCLS) {
        float acc = linb[t];
        for (int f = 0; f < FEAT; ++f) acc += sx[f] * linW[f * NCLS + t];
        acc = acc > 0.0f ? acc : __expf(acc) - 1.0f;
        sl[t] = acc;
    }
    __syncthreads();
    if (t < NCLS) {
        float m = sl[0];
        for (int c = 1; c < NCLS; ++c) m = fmaxf(m, sl[c]);
        float ssum = 0.0f;
        for (int c = 0; c < NCLS; ++c) ssum += __expf(sl[c] - m);
        out[i * NCLS + t] = sl[t] - m - logf(ssum);
    }
}

// ---------------------------------------------------------------------------
extern "C" void kernel_launch(void* const* d_in, const int* in_sizes, int n_in,
                              void* d_out, int out_size, void* d_ws, size_t ws_size,
                              hipStream_t stream) {
    const float* x        = (const float*)d_in[0];
    const float* rel      = (const float*)d_in[1];
    // d_in[2] rel_dict: unused (non-math constant per reference)
    const float* adj      = (const float*)d_in[3];
    const float* adj_ad   = (const float*)d_in[4];
    const float* W_heads  = (const float*)d_in[5];
    const float* a1_heads = (const float*)d_in[6];
    const float* a2_heads = (const float*)d_in[7];
    const float* W_out    = (const float*)d_in[8];
    const float* a1_out   = (const float*)d_in[9];
    const float* a2_out   = (const float*)d_in[10];
    const float* lin_W    = (const float*)d_in[11];
    const float* lin_b    = (const float*)d_in[12];
    float* out = (float*)d_out;

    char* ws = (char*)d_ws;
    bf16_t* Abf  = (bf16_t*)(ws);                                 // 4 MB  [4096,512] bf16
    float*  Hh   = (float*) (ws + (4u  << 20));                   // 8 MB  [4096,512] fp32
    float*  D    = (float*) (ws + (12u << 20));                   // 8 MB  [4096,512] fp32
    bf16_t* WcT  = (bf16_t*)(ws + (20u << 20));                   // 0.5 MB [512,512] bf16 (transposed)
    bf16_t* WoT  = (bf16_t*)(ws + (20u << 20) + (512u << 10));    // 0.5 MB
    float*  f1   = (float*) (ws + (21u << 20));                   // 128 KB [8,4096]
    float*  f2   = (float*) (ws + (21u << 20) + (128u << 10));    // 128 KB
    float*  f1o  = (float*) (ws + (21u << 20) + (256u << 10));    // 16 KB
    float*  f2o  = (float*) (ws + (21u << 20) + (272u << 10));    // 16 KB
    int*    deg  = (int*)   (ws + (21u << 20) + (288u << 10));    // 16 KB
    int*    cols = (int*)   (ws + (22u << 20));                   // 2 MB  [4096,128]
    bf16_t* Hbf  = (bf16_t*)(ws + (24u << 20));                   // 4 MB  [4096,512] bf16 (gather copy)
    // high-water mark 28 MB — round-1 layout used 28 MB and passed.

    // adjacency -> capped CSR (only reader of the 64 MB adj)
    csr_kernel<<<NN, 256, 0, stream>>>(adj, deg, cols);
    // xr = bf16(x + adj_ad @ rel)
    relmm_add_bf16_kernel<<<NN, 128, 0, stream>>>(x, adj_ad, rel, Abf);
    // weight permute/cast (transposed bf16)
    wcatT_kernel<<<1024, 256, 0, stream>>>(W_heads, (unsigned short*)WcT);
    woutT_kernel<<<1024, 256, 0, stream>>>(W_out, (unsigned short*)WoT);
    // H1 (all heads fused) = xr @ Wcat   (bf16 MFMA, fp32 accum, dual store)
    gemm_bf16_kernel<<<dim3(64, 8), 256, 0, stream>>>(Abf, WcT, Hh, (unsigned short*)Hbf);
    // per-head f1/f2 (fp32 H)
    headdot_kernel<<<dim3(NN, 2), 256, 0, stream>>>(Hh, a1_heads, a2_heads, f1, f2);
    // layer-1 sparse attention + ELU -> hcat (bf16 gather)
    att1_kernel<<<NN, 512, 0, stream>>>(Hbf, f1, f2, deg, cols, D);
    // xr2 = bf16(hcat + adj_ad @ rel)
    relmm_add_bf16_kernel<<<NN, 128, 0, stream>>>(D, adj_ad, rel, Abf);
    // h2 = xr2 @ W_out (dual store)
    gemm_bf16_kernel<<<dim3(64, 8), 256, 0, stream>>>(Abf, WoT, Hh, (unsigned short*)Hbf);
    // f1o/f2o (fp32 H)
    rowdot_kernel<<<NN, 256, 0, stream>>>(Hh, a1_out, a2_out, f1o, f2o);
    // layer-2 sparse attention -> out2 (bf16 gather)
    att2_kernel<<<NN, 256, 0, stream>>>(Hbf, f1o, f2o, deg, cols, D);
    // classifier + log_softmax
    final_kernel<<<NN, 64, 0, stream>>>(D, lin_W, lin_b, out);
}

// Round 6
// 239.212 us; speedup vs baseline: 1.4493x; 1.0889x over previous
//
#include <hip/hip_runtime.h>

#define NN      4096
#define FEAT    512
#define NHID    64
#define NHEADS  8
#define NCLS    16
#define MAXDEG  128
#define ALPHA   0.2f

typedef __bf16 bf16_t;
typedef __bf16 bf16x8_t __attribute__((ext_vector_type(8)));
typedef float  f32x4_t  __attribute__((ext_vector_type(4)));
typedef unsigned short us8_t __attribute__((ext_vector_type(8)));

__device__ inline unsigned short f2bf(float f) {
    unsigned int u = __float_as_uint(f);
    u += 0x7fffu + ((u >> 16) & 1u);          // round-to-nearest-even
    return (unsigned short)(u >> 16);
}
__device__ inline float bfu2f(unsigned short b) {
    return __uint_as_float(((unsigned int)b) << 16);
}

// ---------------------------------------------------------------------------
// R[i,:] = adj_ad[i,:] @ rel   ([N,64]@[64,512]) — computed ONCE, reused by
// both layers (was recomputed twice before).
__global__ __launch_bounds__(128) void rmm_kernel(
    const float* __restrict__ adj_ad, const float* __restrict__ rel,
    float* __restrict__ R) {
    int i = blockIdx.x;
    int t = threadIdx.x;            // 0..127
    __shared__ float sa[64];
    if (t < 64) sa[t] = adj_ad[i * 64 + t];
    __syncthreads();
    float4 acc = make_float4(0.f, 0.f, 0.f, 0.f);
    for (int r = 0; r < 64; ++r) {
        float a = sa[r];
        float4 rv = ((const float4*)(rel + r * FEAT))[t];
        acc.x += a * rv.x; acc.y += a * rv.y;
        acc.z += a * rv.z; acc.w += a * rv.w;
    }
    ((float4*)(R + (size_t)i * FEAT))[t] = acc;
}

// ---------------------------------------------------------------------------
// out_bf = bf16(in + R), elementwise over [N,FEAT].
__global__ __launch_bounds__(256) void addcast_kernel(
    const float* __restrict__ in, const float* __restrict__ R,
    bf16_t* __restrict__ out) {
    int idx = blockIdx.x * 256 + threadIdx.x;   // float4 index, 524288 total
    float4 a = ((const float4*)in)[idx];
    float4 b = ((const float4*)R)[idx];
    ushort4 o;
    o.x = f2bf(a.x + b.x); o.y = f2bf(a.y + b.y);
    o.z = f2bf(a.z + b.z); o.w = f2bf(a.w + b.w);
    ((ushort4*)out)[idx] = o;
}

// ---------------------------------------------------------------------------
// Merged weight permute/cast:
//   WcT[n][k] = bf16(W_heads[h=n>>6][k][f=n&63]);  WoT[n][k] = bf16(W_out[k][n])
__global__ __launch_bounds__(256) void wperm_kernel(
    const float* __restrict__ Wh, const float* __restrict__ Wo,
    unsigned short* __restrict__ WcT, unsigned short* __restrict__ WoT) {
    int gid = blockIdx.x * 256 + threadIdx.x;
    if (gid < 262144) {
        int idx = gid;
        int n = idx >> 9, k = idx & 511;
        int h = n >> 6, f = n & 63;
        WcT[idx] = f2bf(Wh[(h * 512 + k) * 64 + f]);
    } else {
        int idx = gid - 262144;
        int n = idx >> 9, k = idx & 511;
        WoT[idx] = f2bf(Wo[k * 512 + n]);
    }
}

// ---------------------------------------------------------------------------
// Cbf[4096,512] bf16 = A[4096,512] bf16 @ Bt^T (Bt [n][k] bf16), fp32 accum.
// Fused epilogue computes f1/f2 attention dots from the fp32 accumulators:
//   layer1 (layer2=0): f1[blockIdx.y*NN + row] = dot (direct store)
//   layer2 (layer2=1): atomicAdd(&f1[row], partial-dot over this bn slice)
// a1/a2 are indexed [bn + local_col] — valid for both layers (a1_heads flat
// IS the head-concat 512-vector; a1_out is a plain 512-vector).
__global__ __launch_bounds__(256) void gemm_bf16_dot_kernel(
    const bf16_t* __restrict__ A, const bf16_t* __restrict__ Bt,
    unsigned short* __restrict__ Cbf,
    const float* __restrict__ a1, const float* __restrict__ a2,
    float* __restrict__ f1, float* __restrict__ f2, int layer2) {
    __shared__ __align__(16) bf16_t As[64][72];   // pitch 72 elems = 144 B
    __shared__ __align__(16) bf16_t Bs[64][72];
    const int bm = blockIdx.x * 64;
    const int bn = blockIdx.y * 64;
    const int t  = threadIdx.x;
    const int lr = t >> 3;            // 0..31 staging row
    const int lc = (t & 7) * 8;       // staging col (elems)
    const int l  = t & 63;
    const int w  = t >> 6;
    const int mrow = w * 16 + (l & 15);
    const int nrow = l & 15;
    const int q8 = (l >> 4) * 8;

    f32x4_t acc[4] = {};
    for (int k0 = 0; k0 < FEAT; k0 += 64) {
        *(uint4*)&As[lr][lc]      = *(const uint4*)(A  + (size_t)(bm + lr)      * FEAT + k0 + lc);
        *(uint4*)&As[32 + lr][lc] = *(const uint4*)(A  + (size_t)(bm + 32 + lr) * FEAT + k0 + lc);
        *(uint4*)&Bs[lr][lc]      = *(const uint4*)(Bt + (size_t)(bn + lr)      * FEAT + k0 + lc);
        *(uint4*)&Bs[32 + lr][lc] = *(const uint4*)(Bt + (size_t)(bn + 32 + lr) * FEAT + k0 + lc);
        __syncthreads();
        #pragma unroll
        for (int kk = 0; kk < 64; kk += 32) {
            bf16x8_t a = *(const bf16x8_t*)&As[mrow][kk + q8];
            #pragma unroll
            for (int nt = 0; nt < 4; ++nt) {
                bf16x8_t b = *(const bf16x8_t*)&Bs[nt * 16 + nrow][kk + q8];
                acc[nt] = __builtin_amdgcn_mfma_f32_16x16x32_bf16(a, b, acc[nt], 0, 0, 0);
            }
        }
        __syncthreads();
    }
    // C/D layout: col = lane&15, row = (lane>>4)*4 + reg
    const int crow = bm + w * 16 + (l >> 4) * 4;
    const int ccol = bn + (l & 15);
    #pragma unroll
    for (int nt = 0; nt < 4; ++nt)
        #pragma unroll
        for (int r = 0; r < 4; ++r)
            Cbf[(size_t)(crow + r) * FEAT + ccol + nt * 16] = f2bf(acc[nt][r]);

    // fused f1/f2 dots on fp32 accumulators
    float a1v[4], a2v[4];
    #pragma unroll
    for (int nt = 0; nt < 4; ++nt) {
        a1v[nt] = a1[bn + (l & 15) + nt * 16];
        a2v[nt] = a2[bn + (l & 15) + nt * 16];
    }
    float p1[4] = {}, p2[4] = {};
    #pragma unroll
    for (int nt = 0; nt < 4; ++nt)
        #pragma unroll
        for (int r = 0; r < 4; ++r) {
            p1[r] += acc[nt][r] * a1v[nt];
            p2[r] += acc[nt][r] * a2v[nt];
        }
    #pragma unroll
    for (int off = 1; off <= 8; off <<= 1)
        #pragma unroll
        for (int r = 0; r < 4; ++r) {
            p1[r] += __shfl_xor(p1[r], off);
            p2[r] += __shfl_xor(p2[r], off);
        }
    if ((l & 15) == 0) {
        int row = bm + w * 16 + (l >> 4) * 4;
        if (layer2) {
            #pragma unroll
            for (int r = 0; r < 4; ++r) {
                atomicAdd(&f1[row + r], p1[r]);
                atomicAdd(&f2[row + r], p2[r]);
            }
        } else {
            #pragma unroll
            for (int r = 0; r < 4; ++r) {
                f1[blockIdx.y * NN + row + r] = p1[r];
                f2[blockIdx.y * NN + row + r] = p2[r];
            }
        }
    }
}

// ---------------------------------------------------------------------------
// zero f1o/f2o (8192 floats) — required every launch (ws re-poisoned).
__global__ __launch_bounds__(256) void initf_kernel(float* __restrict__ f1o,
                                                    float* __restrict__ f2o) {
    int idx = blockIdx.x * 256 + threadIdx.x;   // 0..1023, float4
    ((float4*)f1o)[idx] = make_float4(0.f, 0.f, 0.f, 0.f);
    ((float4*)f2o)[idx] = make_float4(0.f, 0.f, 0.f, 0.f);
}

// ---------------------------------------------------------------------------
// CSR build, float4 scan (unordered cols; downstream sums are order-indep).
__global__ __launch_bounds__(256) void csr_kernel(
    const float* __restrict__ adj, int* __restrict__ deg, int* __restrict__ cols) {
    int i = blockIdx.x;
    __shared__ int cnt;
    if (threadIdx.x == 0) cnt = 0;
    __syncthreads();
    const float4* row4 = (const float4*)(adj + (size_t)i * NN);
    for (int j4 = threadIdx.x; j4 < NN / 4; j4 += 256) {
        float4 v = row4[j4];
        int j = j4 * 4;
        if (v.x > 0.0f) { int p = atomicAdd(&cnt, 1); if (p < MAXDEG) cols[i * MAXDEG + p] = j; }
        if (v.y > 0.0f) { int p = atomicAdd(&cnt, 1); if (p < MAXDEG) cols[i * MAXDEG + p] = j + 1; }
        if (v.z > 0.0f) { int p = atomicAdd(&cnt, 1); if (p < MAXDEG) cols[i * MAXDEG + p] = j + 2; }
        if (v.w > 0.0f) { int p = atomicAdd(&cnt, 1); if (p < MAXDEG) cols[i * MAXDEG + p] = j + 3; }
    }
    __syncthreads();
    if (threadIdx.x == 0) deg[i] = cnt > MAXDEG ? MAXDEG : cnt;
}

// ---------------------------------------------------------------------------
// Layer-1 sparse attention + ELU + fused (+R, bf16 cast) epilogue.
// Block = 512 (8 waves = heads); emits Abf2 = bf16(elu(att@h) + R) directly.
__global__ __launch_bounds__(512) void att1_kernel(
    const bf16_t* __restrict__ Hbf, const float* __restrict__ f1,
    const float* __restrict__ f2, const int* __restrict__ deg,
    const int* __restrict__ cols, const float* __restrict__ R,
    bf16_t* __restrict__ outbf) {
    int i = blockIdx.x;
    int h = threadIdx.x >> 6;
    int l = threadIdx.x & 63;
    __shared__ int jl[MAXDEG];
    __shared__ float se[NHEADS][MAXDEG];
    __shared__ int sdeg;
    if (threadIdx.x == 0) sdeg = deg[i];
    __syncthreads();
    int d = sdeg;
    int dpad = (d + 15) & ~15;
    for (int k = threadIdx.x; k < dpad; k += 512)
        jl[k] = (k < d) ? cols[i * MAXDEG + k] : i;   // pad: self, weight 0
    __syncthreads();
    float fi = f1[h * NN + i];
    // pass 1: scores + wave max
    float lmax = -1e30f;
    for (int k = l; k < d; k += 64) {
        float e = fi + f2[h * NN + jl[k]];
        e = e > 0.0f ? e : ALPHA * e;
        se[h][k] = e;
        lmax = fmaxf(lmax, e);
    }
    for (int off = 32; off; off >>= 1) lmax = fmaxf(lmax, __shfl_down(lmax, off));
    float m = __shfl(lmax, 0);
    // pass 2: exp + wave sum; zero the pad region
    float ls = 0.0f;
    for (int k = l; k < d; k += 64) {
        float p = __expf(se[h][k] - m);
        se[h][k] = p;
        ls += p;
    }
    for (int k = d + l; k < dpad; k += 64) se[h][k] = 0.0f;
    for (int off = 32; off; off >>= 1) ls += __shfl_down(ls, off);
    float s = __shfl(ls, 0);
    // se[h][*] is written and read only by wave h — wave-internal ordering OK.
    // pass 3: neighbor-parallel bf16 gather (branch-free, padded)
    const int slot = l >> 3;          // 0..7
    const int cg   = l & 7;           // col group (8 bf16 = 16 B)
    float acc[8] = {};
    for (int k0 = 0; k0 < dpad; k0 += 16) {
        int ka = k0 + slot;
        int kb = k0 + 8 + slot;
        float pa = se[h][ka];
        us8_t va = *(const us8_t*)(Hbf + (size_t)jl[ka] * FEAT + h * 64 + cg * 8);
        float pb = (kb < dpad) ? se[h][kb] : 0.0f;
        us8_t vb = (kb < dpad) ? *(const us8_t*)(Hbf + (size_t)jl[kb] * FEAT + h * 64 + cg * 8)
                               : va;
        #pragma unroll
        for (int j = 0; j < 8; ++j) acc[j] += pa * bfu2f(va[j]);
        #pragma unroll
        for (int j = 0; j < 8; ++j) acc[j] += pb * bfu2f(vb[j]);
    }
    // combine the 8 neighbor slots (lanes sharing cg differ in bits 3..5)
    #pragma unroll
    for (int off = 8; off <= 32; off <<= 1)
        #pragma unroll
        for (int j = 0; j < 8; ++j) acc[j] += __shfl_xor(acc[j], off);
    if (slot == 0) {
        float inv = 1.0f / s;
        const float* Rrow = R + (size_t)i * FEAT + h * 64 + cg * 8;
        float4 r0 = *(const float4*)(Rrow);
        float4 r1 = *(const float4*)(Rrow + 4);
        float o[8];
        #pragma unroll
        for (int j = 0; j < 8; ++j) {
            float v = acc[j] * inv;
            o[j] = v > 0.0f ? v : __expf(v) - 1.0f;    // ELU
        }
        o[0] += r0.x; o[1] += r0.y; o[2] += r0.z; o[3] += r0.w;
        o[4] += r1.x; o[5] += r1.y; o[6] += r1.z; o[7] += r1.w;
        ushort4 pk0, pk1;
        pk0.x = f2bf(o[0]); pk0.y = f2bf(o[1]); pk0.z = f2bf(o[2]); pk0.w = f2bf(o[3]);
        pk1.x = f2bf(o[4]); pk1.y = f2bf(o[5]); pk1.z = f2bf(o[6]); pk1.w = f2bf(o[7]);
        ushort4* dst = (ushort4*)(outbf + (size_t)i * FEAT + h * 64 + cg * 8);
        dst[0] = pk0;
        dst[1] = pk1;
    }
}

// ---------------------------------------------------------------------------
// Layer-2 sparse attention, bf16 gather (Fout=512, no ELU). Block = 256.
__global__ __launch_bounds__(256) void att2_kernel(
    const bf16_t* __restrict__ Hbf, const float* __restrict__ f1,
    const float* __restrict__ f2, const int* __restrict__ deg,
    const int* __restrict__ cols, float* __restrict__ out) {
    int i = blockIdx.x;
    int t = threadIdx.x;
    __shared__ int jl[MAXDEG];
    __shared__ float sp[MAXDEG];
    __shared__ float red[4];
    __shared__ float part[3][FEAT];
    __shared__ int sdeg;
    if (t == 0) sdeg = deg[i];
    __syncthreads();
    int d = sdeg;
    int dpad = (d + 7) & ~7;
    if (t < dpad) jl[t] = (t < d) ? cols[i * MAXDEG + t] : i;
    __syncthreads();
    float e = 0.0f, lmax = -1e30f;
    if (t < d) {
        e = f1[i] + f2[jl[t]];
        e = e > 0.0f ? e : ALPHA * e;
        lmax = e;
    }
    for (int off = 32; off; off >>= 1) lmax = fmaxf(lmax, __shfl_down(lmax, off));
    if ((t & 63) == 0) red[t >> 6] = lmax;
    __syncthreads();
    float m = fmaxf(fmaxf(red[0], red[1]), fmaxf(red[2], red[3]));
    float p = 0.0f;
    if (t < d) p = __expf(e - m);
    if (t < dpad) sp[t] = p;               // pads write 0
    float ls = p;
    for (int off = 32; off; off >>= 1) ls += __shfl_down(ls, off);
    __syncthreads();                       // red[] reads done before overwrite
    if ((t & 63) == 0) red[t >> 6] = ls;
    __syncthreads();                       // publishes sp[] + red[]
    float s = red[0] + red[1] + red[2] + red[3];
    float inv = 1.0f / s;
    // neighbor-parallel bf16 gather (branch-free, padded)
    const int slot = t >> 6;          // 0..3 (wave id)
    const int cg   = t & 63;          // col group (8 bf16)
    float acc[8] = {};
    for (int k0 = 0; k0 < dpad; k0 += 8) {
        int ka = k0 + slot;
        int kb = k0 + 4 + slot;
        float pa = sp[ka];
        us8_t va = *(const us8_t*)(Hbf + (size_t)jl[ka] * FEAT + cg * 8);
        float pb = (kb < dpad) ? sp[kb] : 0.0f;
        us8_t vb = (kb < dpad) ? *(const us8_t*)(Hbf + (size_t)jl[kb] * FEAT + cg * 8) : va;
        #pragma unroll
        for (int j = 0; j < 8; ++j) acc[j] += pa * bfu2f(va[j]);
        #pragma unroll
        for (int j = 0; j < 8; ++j) acc[j] += pb * bfu2f(vb[j]);
    }
    // combine slots 1..3 into slot 0 via LDS
    if (slot > 0) {
        float* dst = &part[slot - 1][cg * 8];
        *(float4*)(dst)     = make_float4(acc[0], acc[1], acc[2], acc[3]);
        *(float4*)(dst + 4) = make_float4(acc[4], acc[5], acc[6], acc[7]);
    }
    __syncthreads();
    if (slot == 0) {
        #pragma unroll
        for (int sl = 0; sl < 3; ++sl)
            #pragma unroll
            for (int j = 0; j < 8; ++j) acc[j] += part[sl][cg * 8 + j];
        float* dst = out + (size_t)i * FEAT + cg * 8;
        *(float4*)(dst)     = make_float4(acc[0] * inv, acc[1] * inv, acc[2] * inv, acc[3] * inv);
        *(float4*)(dst + 4) = make_float4(acc[4] * inv, acc[5] * inv, acc[6] * inv, acc[7] * inv);
    }
}

// ---------------------------------------------------------------------------
// logits = elu(X @ lin_W + b); out = log_softmax(logits). One block/row.
__global__ __launch_bounds__(64) void final_kernel(
    const float* __restrict__ X, const float* __restrict__ linW,
    const float* __restrict__ linb, float* __restrict__ out) {
    int i = blockIdx.x;
    int t = threadIdx.x;
    __shared__ float sx[FEAT];
    __shared__ float sl[NCLS];
    for (int f = t; f < FEAT; f += 64) sx[f] = X[(size_t)i * FEAT + f];
    __syncthreads();
    if (t < NCLS) {
        float acc = linb[t];
        for (int f = 0; f < FEAT; ++f) acc += sx[f] * linW[f * NCLS + t];
        acc = acc > 0.0f ? acc : __expf(acc) - 1.0f;
        sl[t] = acc;
    }
    __syncthreads();
    if (t < NCLS) {
        float m = sl[0];
        for (int c = 1; c < NCLS; ++c) m = fmaxf(m, sl[c]);
        float ssum = 0.0f;
        for (int c = 0; c < NCLS; ++c) ssum += __expf(sl[c] - m);
        out[i * NCLS + t] = sl[t] - m - logf(ssum);
    }
}

// ---------------------------------------------------------------------------
extern "C" void kernel_launch(void* const* d_in, const int* in_sizes, int n_in,
                              void* d_out, int out_size, void* d_ws, size_t ws_size,
                              hipStream_t stream) {
    const float* x        = (const float*)d_in[0];
    const float* rel      = (const float*)d_in[1];
    // d_in[2] rel_dict: unused (non-math constant per reference)
    const float* adj      = (const float*)d_in[3];
    const float* adj_ad   = (const float*)d_in[4];
    const float* W_heads  = (const float*)d_in[5];
    const float* a1_heads = (const float*)d_in[6];
    const float* a2_heads = (const float*)d_in[7];
    const float* W_out    = (const float*)d_in[8];
    const float* a1_out   = (const float*)d_in[9];
    const float* a2_out   = (const float*)d_in[10];
    const float* lin_W    = (const float*)d_in[11];
    const float* lin_b    = (const float*)d_in[12];
    float* out = (float*)d_out;

    char* ws = (char*)d_ws;
    bf16_t* Abf  = (bf16_t*)(ws);                                 // 4 MB  layer-1 GEMM input
    bf16_t* Abf2 = (bf16_t*)(ws + (4u  << 20));                   // 4 MB  layer-2 GEMM input
    bf16_t* Hbf1 = (bf16_t*)(ws + (8u  << 20));                   // 4 MB  layer-1 H (gather)
    bf16_t* Hbf2 = (bf16_t*)(ws + (12u << 20));                   // 4 MB  layer-2 H (gather)
    float*  R    = (float*) (ws + (16u << 20));                   // 8 MB  adj_ad@rel
    float*  D    = (float*) (ws + (24u << 20));                   // 8 MB  att2 out (fp32)
    bf16_t* WcT  = (bf16_t*)(ws + (32u << 20));                   // 0.5 MB
    bf16_t* WoT  = (bf16_t*)(ws + (32u << 20) + (512u << 10));    // 0.5 MB
    float*  f1   = (float*) (ws + (33u << 20));                   // 128 KB [8,4096]
    float*  f2   = (float*) (ws + (33u << 20) + (128u << 10));    // 128 KB
    float*  f1o  = (float*) (ws + (33u << 20) + (256u << 10));    // 16 KB
    float*  f2o  = (float*) (ws + (33u << 20) + (272u << 10));    // 16 KB
    int*    deg  = (int*)   (ws + (33u << 20) + (288u << 10));    // 16 KB
    int*    cols = (int*)   (ws + (34u << 20));                   // 2 MB  [4096,128]

    // adjacency -> capped CSR (only reader of the 64 MB adj)
    csr_kernel<<<NN, 256, 0, stream>>>(adj, deg, cols);
    // R = adj_ad @ rel (once, shared by both layers)
    rmm_kernel<<<NN, 128, 0, stream>>>(adj_ad, rel, R);
    // Abf = bf16(x + R)
    addcast_kernel<<<2048, 256, 0, stream>>>(x, R, Abf);
    // weight permutes (merged)
    wperm_kernel<<<2048, 256, 0, stream>>>(W_heads, W_out, (unsigned short*)WcT, (unsigned short*)WoT);
    // layer-1 GEMM + fused f1/f2 dots (direct store)
    gemm_bf16_dot_kernel<<<dim3(64, 8), 256, 0, stream>>>(
        Abf, WcT, (unsigned short*)Hbf1, a1_heads, a2_heads, f1, f2, 0);
    // layer-1 attention + ELU + (+R, bf16) epilogue -> Abf2
    att1_kernel<<<NN, 512, 0, stream>>>(Hbf1, f1, f2, deg, cols, R, Abf2);
    // zero f1o/f2o for the atomic reduction
    initf_kernel<<<4, 256, 0, stream>>>(f1o, f2o);
    // layer-2 GEMM + fused f1o/f2o dots (atomicAdd across bn blocks)
    gemm_bf16_dot_kernel<<<dim3(64, 8), 256, 0, stream>>>(
        Abf2, WoT, (unsigned short*)Hbf2, a1_out, a2_out, f1o, f2o, 1);
    // layer-2 attention -> D (fp32)
    att2_kernel<<<NN, 256, 0, stream>>>(Hbf2, f1o, f2o, deg, cols, D);
    // classifier + log_softmax
    final_kernel<<<NN, 64, 0, stream>>>(D, lin_W, lin_b, out);
}

// Round 7
// 223.064 us; speedup vs baseline: 1.5542x; 1.0724x over previous
//
#include <hip/hip_runtime.h>

#define NN      4096
#define FEAT    512
#define NHID    64
#define NHEADS  8
#define NCLS    16
#define MAXDEG  128
#define ALPHA   0.2f

typedef __bf16 bf16_t;
typedef __bf16 bf16x8_t __attribute__((ext_vector_type(8)));
typedef float  f32x4_t  __attribute__((ext_vector_type(4)));
typedef unsigned short us8_t __attribute__((ext_vector_type(8)));

__device__ inline unsigned short f2bf(float f) {
    unsigned int u = __float_as_uint(f);
    u += 0x7fffu + ((u >> 16) & 1u);          // round-to-nearest-even
    return (unsigned short)(u >> 16);
}
__device__ inline float bfu2f(unsigned short b) {
    return __uint_as_float(((unsigned int)b) << 16);
}

// ---------------------------------------------------------------------------
// Fused: R[i,:] = adj_ad[i,:] @ rel  AND  Abf[i,:] = bf16(x[i,:] + R[i,:]).
// (Was two kernels; addcast re-read the 8 MB R the first had just written.)
__global__ __launch_bounds__(128) void rmmfuse_kernel(
    const float* __restrict__ adj_ad, const float* __restrict__ rel,
    const float* __restrict__ x, float* __restrict__ R,
    bf16_t* __restrict__ Abf) {
    int i = blockIdx.x;
    int t = threadIdx.x;            // 0..127
    __shared__ float sa[64];
    if (t < 64) sa[t] = adj_ad[i * 64 + t];
    __syncthreads();
    float4 acc = make_float4(0.f, 0.f, 0.f, 0.f);
    for (int r = 0; r < 64; ++r) {
        float a = sa[r];
        float4 rv = ((const float4*)(rel + r * FEAT))[t];
        acc.x += a * rv.x; acc.y += a * rv.y;
        acc.z += a * rv.z; acc.w += a * rv.w;
    }
    ((float4*)(R + (size_t)i * FEAT))[t] = acc;
    float4 xv = ((const float4*)(x + (size_t)i * FEAT))[t];
    ushort4 o;
    o.x = f2bf(acc.x + xv.x); o.y = f2bf(acc.y + xv.y);
    o.z = f2bf(acc.z + xv.z); o.w = f2bf(acc.w + xv.w);
    *(ushort4*)(Abf + (size_t)i * FEAT + 4 * t) = o;
}

// ---------------------------------------------------------------------------
// Merged weight permute/cast:
//   WcT[n][k] = bf16(W_heads[h=n>>6][k][f=n&63]);  WoT[n][k] = bf16(W_out[k][n])
__global__ __launch_bounds__(256) void wperm_kernel(
    const float* __restrict__ Wh, const float* __restrict__ Wo,
    unsigned short* __restrict__ WcT, unsigned short* __restrict__ WoT) {
    int gid = blockIdx.x * 256 + threadIdx.x;
    if (gid < 262144) {
        int idx = gid;
        int n = idx >> 9, k = idx & 511;
        int h = n >> 6, f = n & 63;
        WcT[idx] = f2bf(Wh[(h * 512 + k) * 64 + f]);
    } else {
        int idx = gid - 262144;
        int n = idx >> 9, k = idx & 511;
        WoT[idx] = f2bf(Wo[k * 512 + n]);
    }
}

// ---------------------------------------------------------------------------
// Cbf = A @ Bt^T (bf16 in, fp32 accum, bf16 out) + fused f1/f2 attention dots.
__global__ __launch_bounds__(256) void gemm_bf16_dot_kernel(
    const bf16_t* __restrict__ A, const bf16_t* __restrict__ Bt,
    unsigned short* __restrict__ Cbf,
    const float* __restrict__ a1, const float* __restrict__ a2,
    float* __restrict__ f1, float* __restrict__ f2, int layer2) {
    __shared__ __align__(16) bf16_t As[64][72];   // pitch 72 elems = 144 B
    __shared__ __align__(16) bf16_t Bs[64][72];
    const int bm = blockIdx.x * 64;
    const int bn = blockIdx.y * 64;
    const int t  = threadIdx.x;
    const int lr = t >> 3;            // 0..31 staging row
    const int lc = (t & 7) * 8;       // staging col (elems)
    const int l  = t & 63;
    const int w  = t >> 6;
    const int mrow = w * 16 + (l & 15);
    const int nrow = l & 15;
    const int q8 = (l >> 4) * 8;

    f32x4_t acc[4] = {};
    for (int k0 = 0; k0 < FEAT; k0 += 64) {
        *(uint4*)&As[lr][lc]      = *(const uint4*)(A  + (size_t)(bm + lr)      * FEAT + k0 + lc);
        *(uint4*)&As[32 + lr][lc] = *(const uint4*)(A  + (size_t)(bm + 32 + lr) * FEAT + k0 + lc);
        *(uint4*)&Bs[lr][lc]      = *(const uint4*)(Bt + (size_t)(bn + lr)      * FEAT + k0 + lc);
        *(uint4*)&Bs[32 + lr][lc] = *(const uint4*)(Bt + (size_t)(bn + 32 + lr) * FEAT + k0 + lc);
        __syncthreads();
        #pragma unroll
        for (int kk = 0; kk < 64; kk += 32) {
            bf16x8_t a = *(const bf16x8_t*)&As[mrow][kk + q8];
            #pragma unroll
            for (int nt = 0; nt < 4; ++nt) {
                bf16x8_t b = *(const bf16x8_t*)&Bs[nt * 16 + nrow][kk + q8];
                acc[nt] = __builtin_amdgcn_mfma_f32_16x16x32_bf16(a, b, acc[nt], 0, 0, 0);
            }
        }
        __syncthreads();
    }
    // C/D layout: col = lane&15, row = (lane>>4)*4 + reg
    const int crow = bm + w * 16 + (l >> 4) * 4;
    const int ccol = bn + (l & 15);
    #pragma unroll
    for (int nt = 0; nt < 4; ++nt)
        #pragma unroll
        for (int r = 0; r < 4; ++r)
            Cbf[(size_t)(crow + r) * FEAT + ccol + nt * 16] = f2bf(acc[nt][r]);

    // fused f1/f2 dots on fp32 accumulators
    float a1v[4], a2v[4];
    #pragma unroll
    for (int nt = 0; nt < 4; ++nt) {
        a1v[nt] = a1[bn + (l & 15) + nt * 16];
        a2v[nt] = a2[bn + (l & 15) + nt * 16];
    }
    float p1[4] = {}, p2[4] = {};
    #pragma unroll
    for (int nt = 0; nt < 4; ++nt)
        #pragma unroll
        for (int r = 0; r < 4; ++r) {
            p1[r] += acc[nt][r] * a1v[nt];
            p2[r] += acc[nt][r] * a2v[nt];
        }
    #pragma unroll
    for (int off = 1; off <= 8; off <<= 1)
        #pragma unroll
        for (int r = 0; r < 4; ++r) {
            p1[r] += __shfl_xor(p1[r], off);
            p2[r] += __shfl_xor(p2[r], off);
        }
    if ((l & 15) == 0) {
        int row = bm + w * 16 + (l >> 4) * 4;
        if (layer2) {
            #pragma unroll
            for (int r = 0; r < 4; ++r) {
                atomicAdd(&f1[row + r], p1[r]);
                atomicAdd(&f2[row + r], p2[r]);
            }
        } else {
            #pragma unroll
            for (int r = 0; r < 4; ++r) {
                f1[blockIdx.y * NN + row + r] = p1[r];
                f2[blockIdx.y * NN + row + r] = p2[r];
            }
        }
    }
}

// ---------------------------------------------------------------------------
// zero f1o/f2o (8192 floats) — required every launch (ws re-poisoned).
__global__ __launch_bounds__(256) void initf_kernel(float* __restrict__ f1o,
                                                    float* __restrict__ f2o) {
    int idx = blockIdx.x * 256 + threadIdx.x;   // 0..1023, float4
    ((float4*)f1o)[idx] = make_float4(0.f, 0.f, 0.f, 0.f);
    ((float4*)f2o)[idx] = make_float4(0.f, 0.f, 0.f, 0.f);
}

// ---------------------------------------------------------------------------
// CSR build — ballot compaction: 1 shared atomic per wave per component
// (was ~41 contended per-lane atomics/row). Order-independent downstream.
__device__ inline void csr_emit(unsigned long long m, int lane, int* cnt,
                                int* colrow, int j) {
    if (m) {
        int tot = __popcll(m);
        int base = 0;
        if (lane == 0) base = atomicAdd(cnt, tot);
        base = __shfl(base, 0);
        if (m & (1ULL << lane)) {
            int pos = __popcll(m & ((1ULL << lane) - 1));
            int idx = base + pos;
            if (idx < MAXDEG) colrow[idx] = j;
        }
    }
}
__global__ __launch_bounds__(256) void csr_kernel(
    const float* __restrict__ adj, int* __restrict__ deg, int* __restrict__ cols) {
    int i = blockIdx.x;
    int t = threadIdx.x;
    int lane = t & 63;
    __shared__ int cnt;
    if (t == 0) cnt = 0;
    __syncthreads();
    const float4* row4 = (const float4*)(adj + (size_t)i * NN);
    int* colrow = cols + i * MAXDEG;
    for (int j4 = t; j4 < NN / 4; j4 += 256) {
        float4 v = row4[j4];
        int j = j4 * 4;
        csr_emit(__ballot(v.x > 0.0f), lane, &cnt, colrow, j);
        csr_emit(__ballot(v.y > 0.0f), lane, &cnt, colrow, j + 1);
        csr_emit(__ballot(v.z > 0.0f), lane, &cnt, colrow, j + 2);
        csr_emit(__ballot(v.w > 0.0f), lane, &cnt, colrow, j + 3);
    }
    __syncthreads();
    if (t == 0) deg[i] = cnt > MAXDEG ? MAXDEG : cnt;
}

// ---------------------------------------------------------------------------
// Layer-1 sparse attention + ELU + fused (+R, bf16 cast) epilogue.
// Block = 512 (8 waves = heads); emits Abf2 = bf16(elu(att@h) + R) directly.
__global__ __launch_bounds__(512) void att1_kernel(
    const bf16_t* __restrict__ Hbf, const float* __restrict__ f1,
    const float* __restrict__ f2, const int* __restrict__ deg,
    const int* __restrict__ cols, const float* __restrict__ R,
    bf16_t* __restrict__ outbf) {
    int i = blockIdx.x;
    int h = threadIdx.x >> 6;
    int l = threadIdx.x & 63;
    __shared__ int jl[MAXDEG];
    __shared__ float se[NHEADS][MAXDEG];
    __shared__ int sdeg;
    if (threadIdx.x == 0) sdeg = deg[i];
    __syncthreads();
    int d = sdeg;
    int dpad = (d + 15) & ~15;
    for (int k = threadIdx.x; k < dpad; k += 512)
        jl[k] = (k < d) ? cols[i * MAXDEG + k] : i;   // pad: self, weight 0
    __syncthreads();
    float fi = f1[h * NN + i];
    // pass 1: scores + wave max
    float lmax = -1e30f;
    for (int k = l; k < d; k += 64) {
        float e = fi + f2[h * NN + jl[k]];
        e = e > 0.0f ? e : ALPHA * e;
        se[h][k] = e;
        lmax = fmaxf(lmax, e);
    }
    for (int off = 32; off; off >>= 1) lmax = fmaxf(lmax, __shfl_down(lmax, off));
    float m = __shfl(lmax, 0);
    // pass 2: exp + wave sum; zero the pad region
    float ls = 0.0f;
    for (int k = l; k < d; k += 64) {
        float p = __expf(se[h][k] - m);
        se[h][k] = p;
        ls += p;
    }
    for (int k = d + l; k < dpad; k += 64) se[h][k] = 0.0f;
    for (int off = 32; off; off >>= 1) ls += __shfl_down(ls, off);
    float s = __shfl(ls, 0);
    // se[h][*] is written and read only by wave h — wave-internal ordering OK.
    // pass 3: neighbor-parallel bf16 gather (branch-free, padded)
    const int slot = l >> 3;          // 0..7
    const int cg   = l & 7;           // col group (8 bf16 = 16 B)
    float acc[8] = {};
    for (int k0 = 0; k0 < dpad; k0 += 16) {
        int ka = k0 + slot;
        int kb = k0 + 8 + slot;
        float pa = se[h][ka];
        us8_t va = *(const us8_t*)(Hbf + (size_t)jl[ka] * FEAT + h * 64 + cg * 8);
        float pb = (kb < dpad) ? se[h][kb] : 0.0f;
        us8_t vb = (kb < dpad) ? *(const us8_t*)(Hbf + (size_t)jl[kb] * FEAT + h * 64 + cg * 8)
                               : va;
        #pragma unroll
        for (int j = 0; j < 8; ++j) acc[j] += pa * bfu2f(va[j]);
        #pragma unroll
        for (int j = 0; j < 8; ++j) acc[j] += pb * bfu2f(vb[j]);
    }
    // combine the 8 neighbor slots (lanes sharing cg differ in bits 3..5)
    #pragma unroll
    for (int off = 8; off <= 32; off <<= 1)
        #pragma unroll
        for (int j = 0; j < 8; ++j) acc[j] += __shfl_xor(acc[j], off);
    if (slot == 0) {
        float inv = 1.0f / s;
        const float* Rrow = R + (size_t)i * FEAT + h * 64 + cg * 8;
        float4 r0 = *(const float4*)(Rrow);
        float4 r1 = *(const float4*)(Rrow + 4);
        float o[8];
        #pragma unroll
        for (int j = 0; j < 8; ++j) {
            float v = acc[j] * inv;
            o[j] = v > 0.0f ? v : __expf(v) - 1.0f;    // ELU
        }
        o[0] += r0.x; o[1] += r0.y; o[2] += r0.z; o[3] += r0.w;
        o[4] += r1.x; o[5] += r1.y; o[6] += r1.z; o[7] += r1.w;
        ushort4 pk0, pk1;
        pk0.x = f2bf(o[0]); pk0.y = f2bf(o[1]); pk0.z = f2bf(o[2]); pk0.w = f2bf(o[3]);
        pk1.x = f2bf(o[4]); pk1.y = f2bf(o[5]); pk1.z = f2bf(o[6]); pk1.w = f2bf(o[7]);
        ushort4* dst = (ushort4*)(outbf + (size_t)i * FEAT + h * 64 + cg * 8);
        dst[0] = pk0;
        dst[1] = pk1;
    }
}

// ---------------------------------------------------------------------------
// Layer-2 sparse attention + fused classifier + log_softmax. Block = 256.
// h2 row stays in LDS; logits = elu(h2 @ lin_W + b); out = log_softmax.
__global__ __launch_bounds__(256) void att2_final_kernel(
    const bf16_t* __restrict__ Hbf, const float* __restrict__ f1,
    const float* __restrict__ f2, const int* __restrict__ deg,
    const int* __restrict__ cols, const float* __restrict__ linW,
    const float* __restrict__ linb, float* __restrict__ out) {
    int i = blockIdx.x;
    int t = threadIdx.x;
    __shared__ int jl[MAXDEG];
    __shared__ float sp[MAXDEG];
    __shared__ float red[4];
    __shared__ float part[3][FEAT];
    __shared__ float hrow[FEAT];
    __shared__ float clsred[16][NCLS];
    __shared__ float sl[NCLS];
    __shared__ int sdeg;
    if (t == 0) sdeg = deg[i];
    __syncthreads();
    int d = sdeg;
    int dpad = (d + 7) & ~7;
    if (t < dpad) jl[t] = (t < d) ? cols[i * MAXDEG + t] : i;
    __syncthreads();
    float e = 0.0f, lmax = -1e30f;
    if (t < d) {
        e = f1[i] + f2[jl[t]];
        e = e > 0.0f ? e : ALPHA * e;
        lmax = e;
    }
    for (int off = 32; off; off >>= 1) lmax = fmaxf(lmax, __shfl_down(lmax, off));
    if ((t & 63) == 0) red[t >> 6] = lmax;
    __syncthreads();
    float m = fmaxf(fmaxf(red[0], red[1]), fmaxf(red[2], red[3]));
    float p = 0.0f;
    if (t < d) p = __expf(e - m);
    if (t < dpad) sp[t] = p;               // pads write 0
    float ls = p;
    for (int off = 32; off; off >>= 1) ls += __shfl_down(ls, off);
    __syncthreads();                       // red[] reads done before overwrite
    if ((t & 63) == 0) red[t >> 6] = ls;
    __syncthreads();                       // publishes sp[] + red[]
    float s = red[0] + red[1] + red[2] + red[3];
    float inv = 1.0f / s;
    // neighbor-parallel bf16 gather (branch-free, padded)
    const int slot = t >> 6;          // 0..3 (wave id)
    const int cg   = t & 63;          // col group (8 bf16)
    float acc[8] = {};
    for (int k0 = 0; k0 < dpad; k0 += 8) {
        int ka = k0 + slot;
        int kb = k0 + 4 + slot;
        float pa = sp[ka];
        us8_t va = *(const us8_t*)(Hbf + (size_t)jl[ka] * FEAT + cg * 8);
        float pb = (kb < dpad) ? sp[kb] : 0.0f;
        us8_t vb = (kb < dpad) ? *(const us8_t*)(Hbf + (size_t)jl[kb] * FEAT + cg * 8) : va;
        #pragma unroll
        for (int j = 0; j < 8; ++j) acc[j] += pa * bfu2f(va[j]);
        #pragma unroll
        for (int j = 0; j < 8; ++j) acc[j] += pb * bfu2f(vb[j]);
    }
    // combine slots 1..3 into slot 0; slot 0 publishes h2 row to LDS
    if (slot > 0) {
        float* dst = &part[slot - 1][cg * 8];
        *(float4*)(dst)     = make_float4(acc[0], acc[1], acc[2], acc[3]);
        *(float4*)(dst + 4) = make_float4(acc[4], acc[5], acc[6], acc[7]);
    }
    __syncthreads();
    if (slot == 0) {
        #pragma unroll
        for (int sl2 = 0; sl2 < 3; ++sl2)
            #pragma unroll
            for (int j = 0; j < 8; ++j) acc[j] += part[sl2][cg * 8 + j];
        float* dst = &hrow[cg * 8];
        *(float4*)(dst)     = make_float4(acc[0] * inv, acc[1] * inv, acc[2] * inv, acc[3] * inv);
        *(float4*)(dst + 4) = make_float4(acc[4] * inv, acc[5] * inv, acc[6] * inv, acc[7] * inv);
    }
    __syncthreads();
    // classifier: class c = t&15, segment seg = t>>4 (32 features each)
    {
        int c = t & 15;
        int seg = t >> 4;
        float partial = 0.0f;
        int f0 = seg * 32;
        #pragma unroll 8
        for (int f = f0; f < f0 + 32; ++f) partial += hrow[f] * linW[f * NCLS + c];
        clsred[seg][c] = partial;
    }
    __syncthreads();
    if (t < NCLS) {
        float logit = linb[t];
        #pragma unroll
        for (int seg = 0; seg < 16; ++seg) logit += clsred[seg][t];
        logit = logit > 0.0f ? logit : __expf(logit) - 1.0f;   // ELU
        sl[t] = logit;
    }
    __syncthreads();
    if (t < NCLS) {
        float mm = sl[0];
        #pragma unroll
        for (int c = 1; c < NCLS; ++c) mm = fmaxf(mm, sl[c]);
        float ssum = 0.0f;
        #pragma unroll
        for (int c = 0; c < NCLS; ++c) ssum += __expf(sl[c] - mm);
        out[i * NCLS + t] = sl[t] - mm - logf(ssum);
    }
}

// ---------------------------------------------------------------------------
extern "C" void kernel_launch(void* const* d_in, const int* in_sizes, int n_in,
                              void* d_out, int out_size, void* d_ws, size_t ws_size,
                              hipStream_t stream) {
    const float* x        = (const float*)d_in[0];
    const float* rel      = (const float*)d_in[1];
    // d_in[2] rel_dict: unused (non-math constant per reference)
    const float* adj      = (const float*)d_in[3];
    const float* adj_ad   = (const float*)d_in[4];
    const float* W_heads  = (const float*)d_in[5];
    const float* a1_heads = (const float*)d_in[6];
    const float* a2_heads = (const float*)d_in[7];
    const float* W_out    = (const float*)d_in[8];
    const float* a1_out   = (const float*)d_in[9];
    const float* a2_out   = (const float*)d_in[10];
    const float* lin_W    = (const float*)d_in[11];
    const float* lin_b    = (const float*)d_in[12];
    float* out = (float*)d_out;

    char* ws = (char*)d_ws;
    bf16_t* Abf  = (bf16_t*)(ws);                                 // 4 MB  layer-1 GEMM input
    bf16_t* Abf2 = (bf16_t*)(ws + (4u  << 20));                   // 4 MB  layer-2 GEMM input
    bf16_t* Hbf1 = (bf16_t*)(ws + (8u  << 20));                   // 4 MB  layer-1 H (gather)
    bf16_t* Hbf2 = (bf16_t*)(ws + (12u << 20));                   // 4 MB  layer-2 H (gather)
    float*  R    = (float*) (ws + (16u << 20));                   // 8 MB  adj_ad@rel
    bf16_t* WcT  = (bf16_t*)(ws + (24u << 20));                   // 0.5 MB
    bf16_t* WoT  = (bf16_t*)(ws + (24u << 20) + (512u << 10));    // 0.5 MB
    float*  f1   = (float*) (ws + (25u << 20));                   // 128 KB [8,4096]
    float*  f2   = (float*) (ws + (25u << 20) + (128u << 10));    // 128 KB
    float*  f1o  = (float*) (ws + (25u << 20) + (256u << 10));    // 16 KB
    float*  f2o  = (float*) (ws + (25u << 20) + (272u << 10));    // 16 KB
    int*    deg  = (int*)   (ws + (25u << 20) + (288u << 10));    // 16 KB
    int*    cols = (int*)   (ws + (26u << 20));                   // 2 MB  [4096,128]

    // adjacency -> capped CSR (ballot compaction)
    csr_kernel<<<NN, 256, 0, stream>>>(adj, deg, cols);
    // R = adj_ad @ rel; Abf = bf16(x + R)  (fused)
    rmmfuse_kernel<<<NN, 128, 0, stream>>>(adj_ad, rel, x, R, Abf);
    // weight permutes (merged)
    wperm_kernel<<<2048, 256, 0, stream>>>(W_heads, W_out, (unsigned short*)WcT, (unsigned short*)WoT);
    // layer-1 GEMM + fused f1/f2 dots (direct store)
    gemm_bf16_dot_kernel<<<dim3(64, 8), 256, 0, stream>>>(
        Abf, WcT, (unsigned short*)Hbf1, a1_heads, a2_heads, f1, f2, 0);
    // layer-1 attention + ELU + (+R, bf16) epilogue -> Abf2
    att1_kernel<<<NN, 512, 0, stream>>>(Hbf1, f1, f2, deg, cols, R, Abf2);
    // zero f1o/f2o for the atomic reduction
    initf_kernel<<<4, 256, 0, stream>>>(f1o, f2o);
    // layer-2 GEMM + fused f1o/f2o dots (atomicAdd across bn blocks)
    gemm_bf16_dot_kernel<<<dim3(64, 8), 256, 0, stream>>>(
        Abf2, WoT, (unsigned short*)Hbf2, a1_out, a2_out, f1o, f2o, 1);
    // layer-2 attention + classifier + log_softmax -> out (fused)
    att2_final_kernel<<<NN, 256, 0, stream>>>(Hbf2, f1o, f2o, deg, cols, lin_W, lin_b, out);
}

// Round 8
// 215.903 us; speedup vs baseline: 1.6057x; 1.0332x over previous
//
#include <hip/hip_runtime.h>

#define NN      4096
#define FEAT    512
#define NHID    64
#define NHEADS  8
#define NCLS    16
#define MAXDEG  128
#define ALPHA   0.2f

typedef __bf16 bf16_t;
typedef __bf16 bf16x8_t __attribute__((ext_vector_type(8)));
typedef float  f32x4_t  __attribute__((ext_vector_type(4)));
typedef unsigned short us8_t __attribute__((ext_vector_type(8)));

__device__ inline unsigned short f2bf(float f) {
    unsigned int u = __float_as_uint(f);
    u += 0x7fffu + ((u >> 16) & 1u);          // round-to-nearest-even
    return (unsigned short)(u >> 16);
}
__device__ inline float bfu2f(unsigned short b) {
    return __uint_as_float(((unsigned int)b) << 16);
}

// ---------------------------------------------------------------------------
// Fused: R[i,:] = adj_ad[i,:] @ rel  AND  Abf[i,:] = bf16(x[i,:] + R[i,:]).
__global__ __launch_bounds__(128) void rmmfuse_kernel(
    const float* __restrict__ adj_ad, const float* __restrict__ rel,
    const float* __restrict__ x, float* __restrict__ R,
    bf16_t* __restrict__ Abf) {
    int i = blockIdx.x;
    int t = threadIdx.x;            // 0..127
    __shared__ float sa[64];
    if (t < 64) sa[t] = adj_ad[i * 64 + t];
    __syncthreads();
    float4 acc = make_float4(0.f, 0.f, 0.f, 0.f);
    for (int r = 0; r < 64; ++r) {
        float a = sa[r];
        float4 rv = ((const float4*)(rel + r * FEAT))[t];
        acc.x += a * rv.x; acc.y += a * rv.y;
        acc.z += a * rv.z; acc.w += a * rv.w;
    }
    ((float4*)(R + (size_t)i * FEAT))[t] = acc;
    float4 xv = ((const float4*)(x + (size_t)i * FEAT))[t];
    ushort4 o;
    o.x = f2bf(acc.x + xv.x); o.y = f2bf(acc.y + xv.y);
    o.z = f2bf(acc.z + xv.z); o.w = f2bf(acc.w + xv.w);
    *(ushort4*)(Abf + (size_t)i * FEAT + 4 * t) = o;
}

// ---------------------------------------------------------------------------
// Merged weight permute/cast + f1o/f2o zero-init (tail blocks):
//   WcT[n][k] = bf16(W_heads[h=n>>6][k][f=n&63]);  WoT[n][k] = bf16(W_out[k][n])
__global__ __launch_bounds__(256) void wperm_kernel(
    const float* __restrict__ Wh, const float* __restrict__ Wo,
    unsigned short* __restrict__ WcT, unsigned short* __restrict__ WoT,
    float* __restrict__ f1o, float* __restrict__ f2o) {
    int gid = blockIdx.x * 256 + threadIdx.x;
    if (gid < 262144) {
        int idx = gid;
        int n = idx >> 9, k = idx & 511;
        int h = n >> 6, f = n & 63;
        WcT[idx] = f2bf(Wh[(h * 512 + k) * 64 + f]);
    } else if (gid < 524288) {
        int idx = gid - 262144;
        int n = idx >> 9, k = idx & 511;
        WoT[idx] = f2bf(Wo[k * 512 + n]);
    } else {
        int idx = gid - 524288;          // 0..1023 -> 1024 float4 per array
        ((float4*)f1o)[idx] = make_float4(0.f, 0.f, 0.f, 0.f);
        ((float4*)f2o)[idx] = make_float4(0.f, 0.f, 0.f, 0.f);
    }
}

// ---------------------------------------------------------------------------
// Cbf = A @ Bt^T (bf16 in, fp32 accum, bf16 out) + fused f1/f2 attention dots.
__global__ __launch_bounds__(256) void gemm_bf16_dot_kernel(
    const bf16_t* __restrict__ A, const bf16_t* __restrict__ Bt,
    unsigned short* __restrict__ Cbf,
    const float* __restrict__ a1, const float* __restrict__ a2,
    float* __restrict__ f1, float* __restrict__ f2, int layer2) {
    __shared__ __align__(16) bf16_t As[64][72];   // pitch 72 elems = 144 B
    __shared__ __align__(16) bf16_t Bs[64][72];
    const int bm = blockIdx.x * 64;
    const int bn = blockIdx.y * 64;
    const int t  = threadIdx.x;
    const int lr = t >> 3;            // 0..31 staging row
    const int lc = (t & 7) * 8;       // staging col (elems)
    const int l  = t & 63;
    const int w  = t >> 6;
    const int mrow = w * 16 + (l & 15);
    const int nrow = l & 15;
    const int q8 = (l >> 4) * 8;

    f32x4_t acc[4] = {};
    for (int k0 = 0; k0 < FEAT; k0 += 64) {
        *(uint4*)&As[lr][lc]      = *(const uint4*)(A  + (size_t)(bm + lr)      * FEAT + k0 + lc);
        *(uint4*)&As[32 + lr][lc] = *(const uint4*)(A  + (size_t)(bm + 32 + lr) * FEAT + k0 + lc);
        *(uint4*)&Bs[lr][lc]      = *(const uint4*)(Bt + (size_t)(bn + lr)      * FEAT + k0 + lc);
        *(uint4*)&Bs[32 + lr][lc] = *(const uint4*)(Bt + (size_t)(bn + 32 + lr) * FEAT + k0 + lc);
        __syncthreads();
        #pragma unroll
        for (int kk = 0; kk < 64; kk += 32) {
            bf16x8_t a = *(const bf16x8_t*)&As[mrow][kk + q8];
            #pragma unroll
            for (int nt = 0; nt < 4; ++nt) {
                bf16x8_t b = *(const bf16x8_t*)&Bs[nt * 16 + nrow][kk + q8];
                acc[nt] = __builtin_amdgcn_mfma_f32_16x16x32_bf16(a, b, acc[nt], 0, 0, 0);
            }
        }
        __syncthreads();
    }
    // C/D layout: col = lane&15, row = (lane>>4)*4 + reg
    const int crow = bm + w * 16 + (l >> 4) * 4;
    const int ccol = bn + (l & 15);
    #pragma unroll
    for (int nt = 0; nt < 4; ++nt)
        #pragma unroll
        for (int r = 0; r < 4; ++r)
            Cbf[(size_t)(crow + r) * FEAT + ccol + nt * 16] = f2bf(acc[nt][r]);

    // fused f1/f2 dots on fp32 accumulators
    float a1v[4], a2v[4];
    #pragma unroll
    for (int nt = 0; nt < 4; ++nt) {
        a1v[nt] = a1[bn + (l & 15) + nt * 16];
        a2v[nt] = a2[bn + (l & 15) + nt * 16];
    }
    float p1[4] = {}, p2[4] = {};
    #pragma unroll
    for (int nt = 0; nt < 4; ++nt)
        #pragma unroll
        for (int r = 0; r < 4; ++r) {
            p1[r] += acc[nt][r] * a1v[nt];
            p2[r] += acc[nt][r] * a2v[nt];
        }
    #pragma unroll
    for (int off = 1; off <= 8; off <<= 1)
        #pragma unroll
        for (int r = 0; r < 4; ++r) {
            p1[r] += __shfl_xor(p1[r], off);
            p2[r] += __shfl_xor(p2[r], off);
        }
    if ((l & 15) == 0) {
        int row = bm + w * 16 + (l >> 4) * 4;
        if (layer2) {
            #pragma unroll
            for (int r = 0; r < 4; ++r) {
                atomicAdd(&f1[row + r], p1[r]);
                atomicAdd(&f2[row + r], p2[r]);
            }
        } else {
            #pragma unroll
            for (int r = 0; r < 4; ++r) {
                f1[blockIdx.y * NN + row + r] = p1[r];
                f2[blockIdx.y * NN + row + r] = p2[r];
            }
        }
    }
}

// ---------------------------------------------------------------------------
// CSR build — ballot compaction: 1 shared atomic per wave per component.
__device__ inline void csr_emit(unsigned long long m, int lane, int* cnt,
                                int* colrow, int j) {
    if (m) {
        int tot = __popcll(m);
        int base = 0;
        if (lane == 0) base = atomicAdd(cnt, tot);
        base = __shfl(base, 0);
        if (m & (1ULL << lane)) {
            int pos = __popcll(m & ((1ULL << lane) - 1));
            int idx = base + pos;
            if (idx < MAXDEG) colrow[idx] = j;
        }
    }
}
__global__ __launch_bounds__(256) void csr_kernel(
    const float* __restrict__ adj, int* __restrict__ deg, int* __restrict__ cols) {
    int i = blockIdx.x;
    int t = threadIdx.x;
    int lane = t & 63;
    __shared__ int cnt;
    if (t == 0) cnt = 0;
    __syncthreads();
    const float4* row4 = (const float4*)(adj + (size_t)i * NN);
    int* colrow = cols + i * MAXDEG;
    for (int j4 = t; j4 < NN / 4; j4 += 256) {
        float4 v = row4[j4];
        int j = j4 * 4;
        csr_emit(__ballot(v.x > 0.0f), lane, &cnt, colrow, j);
        csr_emit(__ballot(v.y > 0.0f), lane, &cnt, colrow, j + 1);
        csr_emit(__ballot(v.z > 0.0f), lane, &cnt, colrow, j + 2);
        csr_emit(__ballot(v.w > 0.0f), lane, &cnt, colrow, j + 3);
    }
    __syncthreads();
    if (t == 0) deg[i] = cnt > MAXDEG ? MAXDEG : cnt;
}

// ---------------------------------------------------------------------------
// Layer-1 sparse attention + ELU + fused (+R, bf16 cast) epilogue.
// Phase A: wave h computes head-h scores/softmax (as before).
// Phase B (restructured): each wave-instruction reads ONE full contiguous
// 1 KB neighbor row (uniform base + lane*16 B). Lane l owns output cols
// [8l,8l+8) (head l>>3); scale from se[l>>3][k]. Waves partition neighbors
// (k mod 8 == wave), unroll 4 -> 4 loads in flight. No shuffle combine;
// 8-way partial reduce via LDS.
__global__ __launch_bounds__(512) void att1_kernel(
    const bf16_t* __restrict__ Hbf, const float* __restrict__ f1,
    const float* __restrict__ f2, const int* __restrict__ deg,
    const int* __restrict__ cols, const float* __restrict__ R,
    bf16_t* __restrict__ outbf) {
    int i = blockIdx.x;
    int tid = threadIdx.x;
    int h = tid >> 6;                 // wave id (phase A: head; phase B: slot)
    int l = tid & 63;
    __shared__ int jl[MAXDEG];
    __shared__ float se[NHEADS][MAXDEG];
    __shared__ float part[NHEADS][FEAT];   // 16 KB
    __shared__ float sinv[NHEADS];
    __shared__ int sdeg;
    if (tid == 0) sdeg = deg[i];
    __syncthreads();
    int d = sdeg;
    int dpad = (d + 31) & ~31;        // multiple of 32 (8 waves x 4 unroll)
    for (int k = tid; k < dpad; k += 512)
        jl[k] = (k < d) ? cols[i * MAXDEG + k] : i;   // pad: self, weight 0
    __syncthreads();
    // ---- phase A: scores for head h ----
    float fi = f1[h * NN + i];
    float lmax = -1e30f;
    for (int k = l; k < d; k += 64) {
        float e = fi + f2[h * NN + jl[k]];
        e = e > 0.0f ? e : ALPHA * e;
        se[h][k] = e;
        lmax = fmaxf(lmax, e);
    }
    for (int off = 32; off; off >>= 1) lmax = fmaxf(lmax, __shfl_down(lmax, off));
    float m = __shfl(lmax, 0);
    float ls = 0.0f;
    for (int k = l; k < d; k += 64) {
        float p = __expf(se[h][k] - m);
        se[h][k] = p;
        ls += p;
    }
    for (int k = d + l; k < dpad; k += 64) se[h][k] = 0.0f;
    for (int off = 32; off; off >>= 1) ls += __shfl_down(ls, off);
    if (l == 0) sinv[h] = 1.0f / ls;
    __syncthreads();                  // se/sinv now read cross-wave
    // ---- phase B: whole-row gather ----
    const int myhead = l >> 3;        // head of this lane's output columns
    float acc[8] = {};
    for (int k0 = 0; k0 < dpad; k0 += 32) {
        float pw[4];
        const bf16_t* rp[4];
        #pragma unroll
        for (int j = 0; j < 4; ++j) {
            int k = k0 + j * 8 + h;                  // k < dpad guaranteed
            pw[j] = se[myhead][k];
            rp[j] = Hbf + (size_t)jl[k] * FEAT + l * 8;
        }
        #pragma unroll
        for (int j = 0; j < 4; ++j) {
            us8_t v = *(const us8_t*)rp[j];
            float p = pw[j];
            #pragma unroll
            for (int q = 0; q < 8; ++q) acc[q] += p * bfu2f(v[q]);
        }
    }
    *(float4*)&part[h][l * 8]     = make_float4(acc[0], acc[1], acc[2], acc[3]);
    *(float4*)&part[h][l * 8 + 4] = make_float4(acc[4], acc[5], acc[6], acc[7]);
    __syncthreads();
    // ---- epilogue: thread tid handles output column tid ----
    {
        float sum = 0.0f;
        #pragma unroll
        for (int w2 = 0; w2 < NHEADS; ++w2) sum += part[w2][tid];
        float o = sum * sinv[tid >> 6];
        o = o > 0.0f ? o : __expf(o) - 1.0f;         // ELU
        o += R[(size_t)i * FEAT + tid];
        ((unsigned short*)outbf)[(size_t)i * FEAT + tid] = f2bf(o);
    }
}

// ---------------------------------------------------------------------------
// Layer-2 sparse attention + fused classifier + log_softmax. Block = 256.
// Gather: 4 waves x whole rows, unroll 4 (k0 step 16).
__global__ __launch_bounds__(256) void att2_final_kernel(
    const bf16_t* __restrict__ Hbf, const float* __restrict__ f1,
    const float* __restrict__ f2, const int* __restrict__ deg,
    const int* __restrict__ cols, const float* __restrict__ linW,
    const float* __restrict__ linb, float* __restrict__ out) {
    int i = blockIdx.x;
    int t = threadIdx.x;
    __shared__ int jl[MAXDEG];
    __shared__ float sp[MAXDEG];
    __shared__ float red[4];
    __shared__ float part[3][FEAT];
    __shared__ float hrow[FEAT];
    __shared__ float clsred[16][NCLS];
    __shared__ float sl[NCLS];
    __shared__ int sdeg;
    if (t == 0) sdeg = deg[i];
    __syncthreads();
    int d = sdeg;
    int dpad = (d + 15) & ~15;        // multiple of 16 (4 waves x 4 unroll)
    if (t < dpad) jl[t] = (t < d) ? cols[i * MAXDEG + t] : i;
    __syncthreads();
    float e = 0.0f, lmax = -1e30f;
    if (t < d) {
        e = f1[i] + f2[jl[t]];
        e = e > 0.0f ? e : ALPHA * e;
        lmax = e;
    }
    for (int off = 32; off; off >>= 1) lmax = fmaxf(lmax, __shfl_down(lmax, off));
    if ((t & 63) == 0) red[t >> 6] = lmax;
    __syncthreads();
    float m = fmaxf(fmaxf(red[0], red[1]), fmaxf(red[2], red[3]));
    float p = 0.0f;
    if (t < d) p = __expf(e - m);
    if (t < dpad) sp[t] = p;          // pads write 0
    float ls = p;
    for (int off = 32; off; off >>= 1) ls += __shfl_down(ls, off);
    __syncthreads();                  // red[] reads done before overwrite
    if ((t & 63) == 0) red[t >> 6] = ls;
    __syncthreads();                  // publishes sp[] + red[]
    float s = red[0] + red[1] + red[2] + red[3];
    float inv = 1.0f / s;
    // whole-row gather, unroll 4
    const int slot = t >> 6;          // 0..3 (wave id)
    const int cg   = t & 63;          // col group (8 bf16)
    float acc[8] = {};
    for (int k0 = 0; k0 < dpad; k0 += 16) {
        float pw[4];
        const bf16_t* rp[4];
        #pragma unroll
        for (int j = 0; j < 4; ++j) {
            int k = k0 + j * 4 + slot;               // k < dpad guaranteed
            pw[j] = sp[k];
            rp[j] = Hbf + (size_t)jl[k] * FEAT + cg * 8;
        }
        #pragma unroll
        for (int j = 0; j < 4; ++j) {
            us8_t v = *(const us8_t*)rp[j];
            float pk = pw[j];
            #pragma unroll
            for (int q = 0; q < 8; ++q) acc[q] += pk * bfu2f(v[q]);
        }
    }
    // combine slots 1..3 into slot 0; slot 0 publishes h2 row to LDS
    if (slot > 0) {
        float* dst = &part[slot - 1][cg * 8];
        *(float4*)(dst)     = make_float4(acc[0], acc[1], acc[2], acc[3]);
        *(float4*)(dst + 4) = make_float4(acc[4], acc[5], acc[6], acc[7]);
    }
    __syncthreads();
    if (slot == 0) {
        #pragma unroll
        for (int sl2 = 0; sl2 < 3; ++sl2)
            #pragma unroll
            for (int j = 0; j < 8; ++j) acc[j] += part[sl2][cg * 8 + j];
        float* dst = &hrow[cg * 8];
        *(float4*)(dst)     = make_float4(acc[0] * inv, acc[1] * inv, acc[2] * inv, acc[3] * inv);
        *(float4*)(dst + 4) = make_float4(acc[4] * inv, acc[5] * inv, acc[6] * inv, acc[7] * inv);
    }
    __syncthreads();
    // classifier: class c = t&15, segment seg = t>>4 (32 features each)
    {
        int c = t & 15;
        int seg = t >> 4;
        float partial = 0.0f;
        int f0 = seg * 32;
        #pragma unroll 8
        for (int f = f0; f < f0 + 32; ++f) partial += hrow[f] * linW[f * NCLS + c];
        clsred[seg][c] = partial;
    }
    __syncthreads();
    if (t < NCLS) {
        float logit = linb[t];
        #pragma unroll
        for (int seg = 0; seg < 16; ++seg) logit += clsred[seg][t];
        logit = logit > 0.0f ? logit : __expf(logit) - 1.0f;   // ELU
        sl[t] = logit;
    }
    __syncthreads();
    if (t < NCLS) {
        float mm = sl[0];
        #pragma unroll
        for (int c = 1; c < NCLS; ++c) mm = fmaxf(mm, sl[c]);
        float ssum = 0.0f;
        #pragma unroll
        for (int c = 0; c < NCLS; ++c) ssum += __expf(sl[c] - mm);
        out[i * NCLS + t] = sl[t] - mm - logf(ssum);
    }
}

// ---------------------------------------------------------------------------
extern "C" void kernel_launch(void* const* d_in, const int* in_sizes, int n_in,
                              void* d_out, int out_size, void* d_ws, size_t ws_size,
                              hipStream_t stream) {
    const float* x        = (const float*)d_in[0];
    const float* rel      = (const float*)d_in[1];
    // d_in[2] rel_dict: unused (non-math constant per reference)
    const float* adj      = (const float*)d_in[3];
    const float* adj_ad   = (const float*)d_in[4];
    const float* W_heads  = (const float*)d_in[5];
    const float* a1_heads = (const float*)d_in[6];
    const float* a2_heads = (const float*)d_in[7];
    const float* W_out    = (const float*)d_in[8];
    const float* a1_out   = (const float*)d_in[9];
    const float* a2_out   = (const float*)d_in[10];
    const float* lin_W    = (const float*)d_in[11];
    const float* lin_b    = (const float*)d_in[12];
    float* out = (float*)d_out;

    char* ws = (char*)d_ws;
    bf16_t* Abf  = (bf16_t*)(ws);                                 // 4 MB  layer-1 GEMM input
    bf16_t* Abf2 = (bf16_t*)(ws + (4u  << 20));                   // 4 MB  layer-2 GEMM input
    bf16_t* Hbf1 = (bf16_t*)(ws + (8u  << 20));                   // 4 MB  layer-1 H (gather)
    bf16_t* Hbf2 = (bf16_t*)(ws + (12u << 20));                   // 4 MB  layer-2 H (gather)
    float*  R    = (float*) (ws + (16u << 20));                   // 8 MB  adj_ad@rel
    bf16_t* WcT  = (bf16_t*)(ws + (24u << 20));                   // 0.5 MB
    bf16_t* WoT  = (bf16_t*)(ws + (24u << 20) + (512u << 10));    // 0.5 MB
    float*  f1   = (float*) (ws + (25u << 20));                   // 128 KB [8,4096]
    float*  f2   = (float*) (ws + (25u << 20) + (128u << 10));    // 128 KB
    float*  f1o  = (float*) (ws + (25u << 20) + (256u << 10));    // 16 KB
    float*  f2o  = (float*) (ws + (25u << 20) + (272u << 10));    // 16 KB
    int*    deg  = (int*)   (ws + (25u << 20) + (288u << 10));    // 16 KB
    int*    cols = (int*)   (ws + (26u << 20));                   // 2 MB  [4096,128]

    // adjacency -> capped CSR (ballot compaction)
    csr_kernel<<<NN, 256, 0, stream>>>(adj, deg, cols);
    // R = adj_ad @ rel; Abf = bf16(x + R)  (fused)
    rmmfuse_kernel<<<NN, 128, 0, stream>>>(adj_ad, rel, x, R, Abf);
    // weight permutes + f1o/f2o zero-init (merged; 2052 blocks)
    wperm_kernel<<<2052, 256, 0, stream>>>(W_heads, W_out,
        (unsigned short*)WcT, (unsigned short*)WoT, f1o, f2o);
    // layer-1 GEMM + fused f1/f2 dots (direct store)
    gemm_bf16_dot_kernel<<<dim3(64, 8), 256, 0, stream>>>(
        Abf, WcT, (unsigned short*)Hbf1, a1_heads, a2_heads, f1, f2, 0);
    // layer-1 attention + ELU + (+R, bf16) epilogue -> Abf2
    att1_kernel<<<NN, 512, 0, stream>>>(Hbf1, f1, f2, deg, cols, R, Abf2);
    // layer-2 GEMM + fused f1o/f2o dots (atomicAdd across bn blocks)
    gemm_bf16_dot_kernel<<<dim3(64, 8), 256, 0, stream>>>(
        Abf2, WoT, (unsigned short*)Hbf2, a1_out, a2_out, f1o, f2o, 1);
    // layer-2 attention + classifier + log_softmax -> out (fused)
    att2_final_kernel<<<NN, 256, 0, stream>>>(Hbf2, f1o, f2o, deg, cols, lin_W, lin_b, out);
}

// Round 9
// 198.717 us; speedup vs baseline: 1.7446x; 1.0865x over previous
//
#include <hip/hip_runtime.h>

#define NN      4096
#define FEAT    512
#define NHID    64
#define NHEADS  8
#define NCLS    16
#define MAXDEG  128
#define ALPHA   0.2f

typedef __bf16 bf16_t;
typedef __bf16 bf16x8_t __attribute__((ext_vector_type(8)));
typedef float  f32x4_t  __attribute__((ext_vector_type(4)));
typedef unsigned short us8_t __attribute__((ext_vector_type(8)));

__device__ inline unsigned short f2bf(float f) {
    unsigned int u = __float_as_uint(f);
    u += 0x7fffu + ((u >> 16) & 1u);          // round-to-nearest-even
    return (unsigned short)(u >> 16);
}
__device__ inline float bfu2f(unsigned short b) {
    return __uint_as_float(((unsigned int)b) << 16);
}

// ---------------------------------------------------------------------------
// CSR ballot compaction helper.
__device__ inline void csr_emit(unsigned long long m, int lane, int* cnt,
                                int* colrow, int j) {
    if (m) {
        int tot = __popcll(m);
        int base = 0;
        if (lane == 0) base = atomicAdd(cnt, tot);
        base = __shfl(base, 0);
        if (m & (1ULL << lane)) {
            int pos = __popcll(m & ((1ULL << lane) - 1));
            int idx = base + pos;
            if (idx < MAXDEG) colrow[idx] = j;
        }
    }
}

// ---------------------------------------------------------------------------
// Fused front-end (one launch, 8196 blocks of 256):
//   blocks [0,4096):        CSR build of adj row b
//   blocks [4096,6144):     R = adj_ad@rel, Abf = bf16(x+R)   (2 rows/block)
//   blocks [6144,8196):     weight permutes + f1o/f2o zero-init
// All three parts are mutually independent — merging lets rmm/wperm hide
// under csr's compulsory 64 MB adj scan.
__global__ __launch_bounds__(256) void prep_kernel(
    const float* __restrict__ adj, int* __restrict__ deg, int* __restrict__ cols,
    const float* __restrict__ adj_ad, const float* __restrict__ rel,
    const float* __restrict__ x, float* __restrict__ R, bf16_t* __restrict__ Abf,
    const float* __restrict__ Wh, const float* __restrict__ Wo,
    unsigned short* __restrict__ WcT, unsigned short* __restrict__ WoT,
    float* __restrict__ f1o, float* __restrict__ f2o) {
    int b = blockIdx.x;
    int t = threadIdx.x;
    __shared__ int cnt;
    __shared__ float sa[2][64];
    if (b < NN) {
        // ---- CSR ----
        int lane = t & 63;
        if (t == 0) cnt = 0;
        __syncthreads();
        const float4* row4 = (const float4*)(adj + (size_t)b * NN);
        int* colrow = cols + b * MAXDEG;
        for (int j4 = t; j4 < NN / 4; j4 += 256) {
            float4 v = row4[j4];
            int j = j4 * 4;
            csr_emit(__ballot(v.x > 0.0f), lane, &cnt, colrow, j);
            csr_emit(__ballot(v.y > 0.0f), lane, &cnt, colrow, j + 1);
            csr_emit(__ballot(v.z > 0.0f), lane, &cnt, colrow, j + 2);
            csr_emit(__ballot(v.w > 0.0f), lane, &cnt, colrow, j + 3);
        }
        __syncthreads();
        if (t == 0) deg[b] = cnt > MAXDEG ? MAXDEG : cnt;
    } else if (b < NN + 2048) {
        // ---- R = adj_ad @ rel; Abf = bf16(x + R); 2 rows per block ----
        int half = t >> 7;            // 0..1
        int tt = t & 127;
        int i = (b - NN) * 2 + half;
        if (tt < 64) sa[half][tt] = adj_ad[i * 64 + tt];
        __syncthreads();
        float4 acc = make_float4(0.f, 0.f, 0.f, 0.f);
        for (int r = 0; r < 64; ++r) {
            float a = sa[half][r];
            float4 rv = ((const float4*)(rel + r * FEAT))[tt];
            acc.x += a * rv.x; acc.y += a * rv.y;
            acc.z += a * rv.z; acc.w += a * rv.w;
        }
        ((float4*)(R + (size_t)i * FEAT))[tt] = acc;
        float4 xv = ((const float4*)(x + (size_t)i * FEAT))[tt];
        ushort4 o;
        o.x = f2bf(acc.x + xv.x); o.y = f2bf(acc.y + xv.y);
        o.z = f2bf(acc.z + xv.z); o.w = f2bf(acc.w + xv.w);
        *(ushort4*)(Abf + (size_t)i * FEAT + 4 * tt) = o;
    } else {
        // ---- weight permutes + f1o/f2o zero ----
        int gid = (b - NN - 2048) * 256 + t;
        if (gid < 262144) {
            int idx = gid;
            int n = idx >> 9, k = idx & 511;
            int h = n >> 6, f = n & 63;
            WcT[idx] = f2bf(Wh[(h * 512 + k) * 64 + f]);
        } else if (gid < 524288) {
            int idx = gid - 262144;
            int n = idx >> 9, k = idx & 511;
            WoT[idx] = f2bf(Wo[k * 512 + n]);
        } else {
            int idx = gid - 524288;          // 0..1023 float4 per array
            ((float4*)f1o)[idx] = make_float4(0.f, 0.f, 0.f, 0.f);
            ((float4*)f2o)[idx] = make_float4(0.f, 0.f, 0.f, 0.f);
        }
    }
}

// ---------------------------------------------------------------------------
// Cbf = A @ Bt^T (bf16 in, fp32 accum, bf16 out) + fused f1/f2 attention dots.
// Register double-buffer: K-tile k+1 global loads issue right after the
// barrier, overlapping the MFMA loop of tile k.
__global__ __launch_bounds__(256) void gemm_bf16_dot_kernel(
    const bf16_t* __restrict__ A, const bf16_t* __restrict__ Bt,
    unsigned short* __restrict__ Cbf,
    const float* __restrict__ a1, const float* __restrict__ a2,
    float* __restrict__ f1, float* __restrict__ f2, int layer2) {
    __shared__ __align__(16) bf16_t As[64][72];   // pitch 72 elems = 144 B
    __shared__ __align__(16) bf16_t Bs[64][72];
    const int bm = blockIdx.x * 64;
    const int bn = blockIdx.y * 64;
    const int t  = threadIdx.x;
    const int lr = t >> 3;            // 0..31 staging row
    const int lc = (t & 7) * 8;       // staging col (elems)
    const int l  = t & 63;
    const int w  = t >> 6;
    const int mrow = w * 16 + (l & 15);
    const int nrow = l & 15;
    const int q8 = (l >> 4) * 8;

    const bf16_t* Ap0 = A  + (size_t)(bm + lr)      * FEAT + lc;
    const bf16_t* Ap1 = A  + (size_t)(bm + 32 + lr) * FEAT + lc;
    const bf16_t* Bp0 = Bt + (size_t)(bn + lr)      * FEAT + lc;
    const bf16_t* Bp1 = Bt + (size_t)(bn + 32 + lr) * FEAT + lc;
    uint4 ra0 = *(const uint4*)(Ap0);
    uint4 ra1 = *(const uint4*)(Ap1);
    uint4 rb0 = *(const uint4*)(Bp0);
    uint4 rb1 = *(const uint4*)(Bp1);

    f32x4_t acc[4] = {};
    for (int k0 = 0; k0 < FEAT; k0 += 64) {
        *(uint4*)&As[lr][lc]      = ra0;
        *(uint4*)&As[32 + lr][lc] = ra1;
        *(uint4*)&Bs[lr][lc]      = rb0;
        *(uint4*)&Bs[32 + lr][lc] = rb1;
        __syncthreads();
        if (k0 + 64 < FEAT) {
            ra0 = *(const uint4*)(Ap0 + k0 + 64);
            ra1 = *(const uint4*)(Ap1 + k0 + 64);
            rb0 = *(const uint4*)(Bp0 + k0 + 64);
            rb1 = *(const uint4*)(Bp1 + k0 + 64);
        }
        #pragma unroll
        for (int kk = 0; kk < 64; kk += 32) {
            bf16x8_t a = *(const bf16x8_t*)&As[mrow][kk + q8];
            #pragma unroll
            for (int nt = 0; nt < 4; ++nt) {
                bf16x8_t b = *(const bf16x8_t*)&Bs[nt * 16 + nrow][kk + q8];
                acc[nt] = __builtin_amdgcn_mfma_f32_16x16x32_bf16(a, b, acc[nt], 0, 0, 0);
            }
        }
        __syncthreads();
    }
    // C/D layout: col = lane&15, row = (lane>>4)*4 + reg
    const int crow = bm + w * 16 + (l >> 4) * 4;
    const int ccol = bn + (l & 15);
    #pragma unroll
    for (int nt = 0; nt < 4; ++nt)
        #pragma unroll
        for (int r = 0; r < 4; ++r)
            Cbf[(size_t)(crow + r) * FEAT + ccol + nt * 16] = f2bf(acc[nt][r]);

    // fused f1/f2 dots on fp32 accumulators
    float a1v[4], a2v[4];
    #pragma unroll
    for (int nt = 0; nt < 4; ++nt) {
        a1v[nt] = a1[bn + (l & 15) + nt * 16];
        a2v[nt] = a2[bn + (l & 15) + nt * 16];
    }
    float p1[4] = {}, p2[4] = {};
    #pragma unroll
    for (int nt = 0; nt < 4; ++nt)
        #pragma unroll
        for (int r = 0; r < 4; ++r) {
            p1[r] += acc[nt][r] * a1v[nt];
            p2[r] += acc[nt][r] * a2v[nt];
        }
    #pragma unroll
    for (int off = 1; off <= 8; off <<= 1)
        #pragma unroll
        for (int r = 0; r < 4; ++r) {
            p1[r] += __shfl_xor(p1[r], off);
            p2[r] += __shfl_xor(p2[r], off);
        }
    if ((l & 15) == 0) {
        int row = bm + w * 16 + (l >> 4) * 4;
        if (layer2) {
            #pragma unroll
            for (int r = 0; r < 4; ++r) {
                atomicAdd(&f1[row + r], p1[r]);
                atomicAdd(&f2[row + r], p2[r]);
            }
        } else {
            #pragma unroll
            for (int r = 0; r < 4; ++r) {
                f1[blockIdx.y * NN + row + r] = p1[r];
                f2[blockIdx.y * NN + row + r] = p2[r];
            }
        }
    }
}

// ---------------------------------------------------------------------------
// Layer-1 sparse attention + ELU + fused (+R, bf16 cast) epilogue.
__global__ __launch_bounds__(512) void att1_kernel(
    const bf16_t* __restrict__ Hbf, const float* __restrict__ f1,
    const float* __restrict__ f2, const int* __restrict__ deg,
    const int* __restrict__ cols, const float* __restrict__ R,
    bf16_t* __restrict__ outbf) {
    int i = blockIdx.x;
    int tid = threadIdx.x;
    int h = tid >> 6;                 // wave id (phase A: head; phase B: slot)
    int l = tid & 63;
    __shared__ int jl[MAXDEG];
    __shared__ float se[NHEADS][MAXDEG];
    __shared__ float part[NHEADS][FEAT];   // 16 KB
    __shared__ float sinv[NHEADS];
    __shared__ int sdeg;
    if (tid == 0) sdeg = deg[i];
    __syncthreads();
    int d = sdeg;
    int dpad = (d + 31) & ~31;        // multiple of 32 (8 waves x 4 unroll)
    for (int k = tid; k < dpad; k += 512)
        jl[k] = (k < d) ? cols[i * MAXDEG + k] : i;   // pad: self, weight 0
    __syncthreads();
    // ---- phase A: scores for head h ----
    float fi = f1[h * NN + i];
    float lmax = -1e30f;
    for (int k = l; k < d; k += 64) {
        float e = fi + f2[h * NN + jl[k]];
        e = e > 0.0f ? e : ALPHA * e;
        se[h][k] = e;
        lmax = fmaxf(lmax, e);
    }
    for (int off = 32; off; off >>= 1) lmax = fmaxf(lmax, __shfl_down(lmax, off));
    float m = __shfl(lmax, 0);
    float ls = 0.0f;
    for (int k = l; k < d; k += 64) {
        float p = __expf(se[h][k] - m);
        se[h][k] = p;
        ls += p;
    }
    for (int k = d + l; k < dpad; k += 64) se[h][k] = 0.0f;
    for (int off = 32; off; off >>= 1) ls += __shfl_down(ls, off);
    if (l == 0) sinv[h] = 1.0f / ls;
    __syncthreads();                  // se/sinv now read cross-wave
    // ---- phase B: whole-row gather (wave h takes k ≡ h mod 8, unroll 4) ----
    const int myhead = l >> 3;        // head of this lane's output columns
    float acc[8] = {};
    for (int k0 = 0; k0 < dpad; k0 += 32) {
        float pw[4];
        const bf16_t* rp[4];
        #pragma unroll
        for (int j = 0; j < 4; ++j) {
            int k = k0 + j * 8 + h;                  // k < dpad guaranteed
            pw[j] = se[myhead][k];
            rp[j] = Hbf + (size_t)jl[k] * FEAT + l * 8;
        }
        #pragma unroll
        for (int j = 0; j < 4; ++j) {
            us8_t v = *(const us8_t*)rp[j];
            float p = pw[j];
            #pragma unroll
            for (int q = 0; q < 8; ++q) acc[q] += p * bfu2f(v[q]);
        }
    }
    *(float4*)&part[h][l * 8]     = make_float4(acc[0], acc[1], acc[2], acc[3]);
    *(float4*)&part[h][l * 8 + 4] = make_float4(acc[4], acc[5], acc[6], acc[7]);
    __syncthreads();
    // ---- epilogue: thread tid handles output column tid ----
    {
        float sum = 0.0f;
        #pragma unroll
        for (int w2 = 0; w2 < NHEADS; ++w2) sum += part[w2][tid];
        float o = sum * sinv[tid >> 6];
        o = o > 0.0f ? o : __expf(o) - 1.0f;         // ELU
        o += R[(size_t)i * FEAT + tid];
        ((unsigned short*)outbf)[(size_t)i * FEAT + tid] = f2bf(o);
    }
}

// ---------------------------------------------------------------------------
// Layer-2 sparse attention + fused classifier + log_softmax. Block = 256.
__global__ __launch_bounds__(256) void att2_final_kernel(
    const bf16_t* __restrict__ Hbf, const float* __restrict__ f1,
    const float* __restrict__ f2, const int* __restrict__ deg,
    const int* __restrict__ cols, const float* __restrict__ linW,
    const float* __restrict__ linb, float* __restrict__ out) {
    int i = blockIdx.x;
    int t = threadIdx.x;
    __shared__ int jl[MAXDEG];
    __shared__ float sp[MAXDEG];
    __shared__ float red[4];
    __shared__ float part[3][FEAT];
    __shared__ float hrow[FEAT];
    __shared__ float clsred[16][NCLS];
    __shared__ float sl[NCLS];
    __shared__ int sdeg;
    if (t == 0) sdeg = deg[i];
    __syncthreads();
    int d = sdeg;
    int dpad = (d + 15) & ~15;        // multiple of 16 (4 waves x 4 unroll)
    if (t < dpad) jl[t] = (t < d) ? cols[i * MAXDEG + t] : i;
    __syncthreads();
    float e = 0.0f, lmax = -1e30f;
    if (t < d) {
        e = f1[i] + f2[jl[t]];
        e = e > 0.0f ? e : ALPHA * e;
        lmax = e;
    }
    for (int off = 32; off; off >>= 1) lmax = fmaxf(lmax, __shfl_down(lmax, off));
    if ((t & 63) == 0) red[t >> 6] = lmax;
    __syncthreads();
    float m = fmaxf(fmaxf(red[0], red[1]), fmaxf(red[2], red[3]));
    float p = 0.0f;
    if (t < d) p = __expf(e - m);
    if (t < dpad) sp[t] = p;          // pads write 0
    float ls = p;
    for (int off = 32; off; off >>= 1) ls += __shfl_down(ls, off);
    __syncthreads();                  // red[] reads done before overwrite
    if ((t & 63) == 0) red[t >> 6] = ls;
    __syncthreads();                  // publishes sp[] + red[]
    float s = red[0] + red[1] + red[2] + red[3];
    float inv = 1.0f / s;
    // whole-row gather, unroll 4
    const int slot = t >> 6;          // 0..3 (wave id)
    const int cg   = t & 63;          // col group (8 bf16)
    float acc[8] = {};
    for (int k0 = 0; k0 < dpad; k0 += 16) {
        float pw[4];
        const bf16_t* rp[4];
        #pragma unroll
        for (int j = 0; j < 4; ++j) {
            int k = k0 + j * 4 + slot;               // k < dpad guaranteed
            pw[j] = sp[k];
            rp[j] = Hbf + (size_t)jl[k] * FEAT + cg * 8;
        }
        #pragma unroll
        for (int j = 0; j < 4; ++j) {
            us8_t v = *(const us8_t*)rp[j];
            float pk = pw[j];
            #pragma unroll
            for (int q = 0; q < 8; ++q) acc[q] += pk * bfu2f(v[q]);
        }
    }
    // combine slots 1..3 into slot 0; slot 0 publishes h2 row to LDS
    if (slot > 0) {
        float* dst = &part[slot - 1][cg * 8];
        *(float4*)(dst)     = make_float4(acc[0], acc[1], acc[2], acc[3]);
        *(float4*)(dst + 4) = make_float4(acc[4], acc[5], acc[6], acc[7]);
    }
    __syncthreads();
    if (slot == 0) {
        #pragma unroll
        for (int sl2 = 0; sl2 < 3; ++sl2)
            #pragma unroll
            for (int j = 0; j < 8; ++j) acc[j] += part[sl2][cg * 8 + j];
        float* dst = &hrow[cg * 8];
        *(float4*)(dst)     = make_float4(acc[0] * inv, acc[1] * inv, acc[2] * inv, acc[3] * inv);
        *(float4*)(dst + 4) = make_float4(acc[4] * inv, acc[5] * inv, acc[6] * inv, acc[7] * inv);
    }
    __syncthreads();
    // classifier: class c = t&15, segment seg = t>>4 (32 features each)
    {
        int c = t & 15;
        int seg = t >> 4;
        float partial = 0.0f;
        int f0 = seg * 32;
        #pragma unroll 8
        for (int f = f0; f < f0 + 32; ++f) partial += hrow[f] * linW[f * NCLS + c];
        clsred[seg][c] = partial;
    }
    __syncthreads();
    if (t < NCLS) {
        float logit = linb[t];
        #pragma unroll
        for (int seg = 0; seg < 16; ++seg) logit += clsred[seg][t];
        logit = logit > 0.0f ? logit : __expf(logit) - 1.0f;   // ELU
        sl[t] = logit;
    }
    __syncthreads();
    if (t < NCLS) {
        float mm = sl[0];
        #pragma unroll
        for (int c = 1; c < NCLS; ++c) mm = fmaxf(mm, sl[c]);
        float ssum = 0.0f;
        #pragma unroll
        for (int c = 0; c < NCLS; ++c) ssum += __expf(sl[c] - mm);
        out[i * NCLS + t] = sl[t] - mm - logf(ssum);
    }
}

// ---------------------------------------------------------------------------
extern "C" void kernel_launch(void* const* d_in, const int* in_sizes, int n_in,
                              void* d_out, int out_size, void* d_ws, size_t ws_size,
                              hipStream_t stream) {
    const float* x        = (const float*)d_in[0];
    const float* rel      = (const float*)d_in[1];
    // d_in[2] rel_dict: unused (non-math constant per reference)
    const float* adj      = (const float*)d_in[3];
    const float* adj_ad   = (const float*)d_in[4];
    const float* W_heads  = (const float*)d_in[5];
    const float* a1_heads = (const float*)d_in[6];
    const float* a2_heads = (const float*)d_in[7];
    const float* W_out    = (const float*)d_in[8];
    const float* a1_out   = (const float*)d_in[9];
    const float* a2_out   = (const float*)d_in[10];
    const float* lin_W    = (const float*)d_in[11];
    const float* lin_b    = (const float*)d_in[12];
    float* out = (float*)d_out;

    char* ws = (char*)d_ws;
    bf16_t* Abf  = (bf16_t*)(ws);                                 // 4 MB  layer-1 GEMM input
    bf16_t* Abf2 = (bf16_t*)(ws + (4u  << 20));                   // 4 MB  layer-2 GEMM input
    bf16_t* Hbf1 = (bf16_t*)(ws + (8u  << 20));                   // 4 MB  layer-1 H (gather)
    bf16_t* Hbf2 = (bf16_t*)(ws + (12u << 20));                   // 4 MB  layer-2 H (gather)
    float*  R    = (float*) (ws + (16u << 20));                   // 8 MB  adj_ad@rel
    bf16_t* WcT  = (bf16_t*)(ws + (24u << 20));                   // 0.5 MB
    bf16_t* WoT  = (bf16_t*)(ws + (24u << 20) + (512u << 10));    // 0.5 MB
    float*  f1   = (float*) (ws + (25u << 20));                   // 128 KB [8,4096]
    float*  f2   = (float*) (ws + (25u << 20) + (128u << 10));    // 128 KB
    float*  f1o  = (float*) (ws + (25u << 20) + (256u << 10));    // 16 KB
    float*  f2o  = (float*) (ws + (25u << 20) + (272u << 10));    // 16 KB
    int*    deg  = (int*)   (ws + (25u << 20) + (288u << 10));    // 16 KB
    int*    cols = (int*)   (ws + (26u << 20));                   // 2 MB  [4096,128]

    // fused front-end: CSR + (R, Abf) + weight permutes + f-zero
    prep_kernel<<<NN + 2048 + 2052, 256, 0, stream>>>(
        adj, deg, cols, adj_ad, rel, x, R, Abf,
        W_heads, W_out, (unsigned short*)WcT, (unsigned short*)WoT, f1o, f2o);
    // layer-1 GEMM + fused f1/f2 dots (direct store)
    gemm_bf16_dot_kernel<<<dim3(64, 8), 256, 0, stream>>>(
        Abf, WcT, (unsigned short*)Hbf1, a1_heads, a2_heads, f1, f2, 0);
    // layer-1 attention + ELU + (+R, bf16) epilogue -> Abf2
    att1_kernel<<<NN, 512, 0, stream>>>(Hbf1, f1, f2, deg, cols, R, Abf2);
    // layer-2 GEMM + fused f1o/f2o dots (atomicAdd across bn blocks)
    gemm_bf16_dot_kernel<<<dim3(64, 8), 256, 0, stream>>>(
        Abf2, WoT, (unsigned short*)Hbf2, a1_out, a2_out, f1o, f2o, 1);
    // layer-2 attention + classifier + log_softmax -> out (fused)
    att2_final_kernel<<<NN, 256, 0, stream>>>(Hbf2, f1o, f2o, deg, cols, lin_W, lin_b, out);
}

// Round 10
// 194.949 us; speedup vs baseline: 1.7783x; 1.0193x over previous
//
#include <hip/hip_runtime.h>

#define NN      4096
#define FEAT    512
#define NHID    64
#define NHEADS  8
#define NCLS    16
#define MAXDEG  128
#define ALPHA   0.2f

typedef __bf16 bf16_t;
typedef __bf16 bf16x8_t __attribute__((ext_vector_type(8)));
typedef float  f32x4_t  __attribute__((ext_vector_type(4)));
typedef unsigned short us8_t __attribute__((ext_vector_type(8)));

__device__ inline unsigned short f2bf(float f) {
    unsigned int u = __float_as_uint(f);
    u += 0x7fffu + ((u >> 16) & 1u);          // round-to-nearest-even
    return (unsigned short)(u >> 16);
}
__device__ inline float bfu2f(unsigned short b) {
    return __uint_as_float(((unsigned int)b) << 16);
}

// ---------------------------------------------------------------------------
// Fused front-end (one launch, 8196 blocks of 256):
//   blocks [0,4096):        CSR build of adj row b (prefix-sum compaction)
//   blocks [4096,6144):     R = adj_ad@rel, Abf = bf16(x+R)   (2 rows/block)
//   blocks [6144,8196):     weight permutes + f1o/f2o zero-init
__global__ __launch_bounds__(256) void prep_kernel(
    const float* __restrict__ adj, int* __restrict__ deg, int* __restrict__ cols,
    const float* __restrict__ adj_ad, const float* __restrict__ rel,
    const float* __restrict__ x, float* __restrict__ R, bf16_t* __restrict__ Abf,
    const float* __restrict__ Wh, const float* __restrict__ Wo,
    unsigned short* __restrict__ WcT, unsigned short* __restrict__ WoT,
    float* __restrict__ f1o, float* __restrict__ f2o) {
    int b = blockIdx.x;
    int t = threadIdx.x;
    __shared__ int wsum[4];
    __shared__ float sa[2][64];
    if (b < NN) {
        // ---- CSR via load-all + prefix-sum compaction (no atomics/ballots).
        // Thread t owns float4s {t, t+256, t+512, t+768} (coalesced loads,
        // 4 independent -> 4 in flight). cols order is thread-interleaved —
        // downstream softmax/accum are order-independent sums.
        const float4* row4 = (const float4*)(adj + (size_t)b * NN);
        float4 v0 = row4[t];
        float4 v1 = row4[t + 256];
        float4 v2 = row4[t + 512];
        float4 v3 = row4[t + 768];
        unsigned mask = 0;
        mask |= (v0.x > 0.0f) << 0;  mask |= (v0.y > 0.0f) << 1;
        mask |= (v0.z > 0.0f) << 2;  mask |= (v0.w > 0.0f) << 3;
        mask |= (v1.x > 0.0f) << 4;  mask |= (v1.y > 0.0f) << 5;
        mask |= (v1.z > 0.0f) << 6;  mask |= (v1.w > 0.0f) << 7;
        mask |= (v2.x > 0.0f) << 8;  mask |= (v2.y > 0.0f) << 9;
        mask |= (v2.z > 0.0f) << 10; mask |= (v2.w > 0.0f) << 11;
        mask |= (v3.x > 0.0f) << 12; mask |= (v3.y > 0.0f) << 13;
        mask |= (v3.z > 0.0f) << 14; mask |= (v3.w > 0.0f) << 15;
        int c = __popc(mask);
        // wave inclusive prefix sum
        int lane = t & 63;
        int pre = c;
        #pragma unroll
        for (int off = 1; off < 64; off <<= 1) {
            int n = __shfl_up(pre, off);
            if (lane >= off) pre += n;
        }
        if (lane == 63) wsum[t >> 6] = pre;
        __syncthreads();
        int base = pre - c;                      // exclusive within wave
        #pragma unroll
        for (int w2 = 0; w2 < 4; ++w2)
            if (w2 < (t >> 6)) base += wsum[w2];
        int* colrow = cols + b * MAXDEG;
        unsigned mm = mask;
        int idx = base;
        while (mm) {
            int bit = __ffs(mm) - 1;
            mm &= mm - 1;
            // element index: quad = bit>>2 (which float4), sub = bit&3
            int j = 4 * t + (bit >> 2) * 1024 + (bit & 3);
            if (idx < MAXDEG) colrow[idx] = j;
            ++idx;
        }
        if (t == 0) {
            int tot = wsum[0] + wsum[1] + wsum[2] + wsum[3];
            deg[b] = tot > MAXDEG ? MAXDEG : tot;
        }
    } else if (b < NN + 2048) {
        // ---- R = adj_ad @ rel; Abf = bf16(x + R); 2 rows per block ----
        int half = t >> 7;            // 0..1
        int tt = t & 127;
        int i = (b - NN) * 2 + half;
        if (tt < 64) sa[half][tt] = adj_ad[i * 64 + tt];
        __syncthreads();
        float4 acc = make_float4(0.f, 0.f, 0.f, 0.f);
        for (int r = 0; r < 64; ++r) {
            float a = sa[half][r];
            float4 rv = ((const float4*)(rel + r * FEAT))[tt];
            acc.x += a * rv.x; acc.y += a * rv.y;
            acc.z += a * rv.z; acc.w += a * rv.w;
        }
        ((float4*)(R + (size_t)i * FEAT))[tt] = acc;
        float4 xv = ((const float4*)(x + (size_t)i * FEAT))[tt];
        ushort4 o;
        o.x = f2bf(acc.x + xv.x); o.y = f2bf(acc.y + xv.y);
        o.z = f2bf(acc.z + xv.z); o.w = f2bf(acc.w + xv.w);
        *(ushort4*)(Abf + (size_t)i * FEAT + 4 * tt) = o;
    } else {
        // ---- weight permutes + f1o/f2o zero ----
        int gid = (b - NN - 2048) * 256 + t;
        if (gid < 262144) {
            int idx = gid;
            int n = idx >> 9, k = idx & 511;
            int h = n >> 6, f = n & 63;
            WcT[idx] = f2bf(Wh[(h * 512 + k) * 64 + f]);
        } else if (gid < 524288) {
            int idx = gid - 262144;
            int n = idx >> 9, k = idx & 511;
            WoT[idx] = f2bf(Wo[k * 512 + n]);
        } else {
            int idx = gid - 524288;          // 0..1023 float4 per array
            ((float4*)f1o)[idx] = make_float4(0.f, 0.f, 0.f, 0.f);
            ((float4*)f2o)[idx] = make_float4(0.f, 0.f, 0.f, 0.f);
        }
    }
}

// ---------------------------------------------------------------------------
// Cbf = A @ Bt^T (bf16 in, fp32 accum, bf16 out) + fused f1/f2 attention dots.
// Register double-buffer: K-tile k+1 global loads issue right after the
// barrier, overlapping the MFMA loop of tile k.
__global__ __launch_bounds__(256) void gemm_bf16_dot_kernel(
    const bf16_t* __restrict__ A, const bf16_t* __restrict__ Bt,
    unsigned short* __restrict__ Cbf,
    const float* __restrict__ a1, const float* __restrict__ a2,
    float* __restrict__ f1, float* __restrict__ f2, int layer2) {
    __shared__ __align__(16) bf16_t As[64][72];   // pitch 72 elems = 144 B
    __shared__ __align__(16) bf16_t Bs[64][72];
    const int bm = blockIdx.x * 64;
    const int bn = blockIdx.y * 64;
    const int t  = threadIdx.x;
    const int lr = t >> 3;            // 0..31 staging row
    const int lc = (t & 7) * 8;       // staging col (elems)
    const int l  = t & 63;
    const int w  = t >> 6;
    const int mrow = w * 16 + (l & 15);
    const int nrow = l & 15;
    const int q8 = (l >> 4) * 8;

    const bf16_t* Ap0 = A  + (size_t)(bm + lr)      * FEAT + lc;
    const bf16_t* Ap1 = A  + (size_t)(bm + 32 + lr) * FEAT + lc;
    const bf16_t* Bp0 = Bt + (size_t)(bn + lr)      * FEAT + lc;
    const bf16_t* Bp1 = Bt + (size_t)(bn + 32 + lr) * FEAT + lc;
    uint4 ra0 = *(const uint4*)(Ap0);
    uint4 ra1 = *(const uint4*)(Ap1);
    uint4 rb0 = *(const uint4*)(Bp0);
    uint4 rb1 = *(const uint4*)(Bp1);

    f32x4_t acc[4] = {};
    for (int k0 = 0; k0 < FEAT; k0 += 64) {
        *(uint4*)&As[lr][lc]      = ra0;
        *(uint4*)&As[32 + lr][lc] = ra1;
        *(uint4*)&Bs[lr][lc]      = rb0;
        *(uint4*)&Bs[32 + lr][lc] = rb1;
        __syncthreads();
        if (k0 + 64 < FEAT) {
            ra0 = *(const uint4*)(Ap0 + k0 + 64);
            ra1 = *(const uint4*)(Ap1 + k0 + 64);
            rb0 = *(const uint4*)(Bp0 + k0 + 64);
            rb1 = *(const uint4*)(Bp1 + k0 + 64);
        }
        #pragma unroll
        for (int kk = 0; kk < 64; kk += 32) {
            bf16x8_t a = *(const bf16x8_t*)&As[mrow][kk + q8];
            #pragma unroll
            for (int nt = 0; nt < 4; ++nt) {
                bf16x8_t b = *(const bf16x8_t*)&Bs[nt * 16 + nrow][kk + q8];
                acc[nt] = __builtin_amdgcn_mfma_f32_16x16x32_bf16(a, b, acc[nt], 0, 0, 0);
            }
        }
        __syncthreads();
    }
    // C/D layout: col = lane&15, row = (lane>>4)*4 + reg
    const int crow = bm + w * 16 + (l >> 4) * 4;
    const int ccol = bn + (l & 15);
    #pragma unroll
    for (int nt = 0; nt < 4; ++nt)
        #pragma unroll
        for (int r = 0; r < 4; ++r)
            Cbf[(size_t)(crow + r) * FEAT + ccol + nt * 16] = f2bf(acc[nt][r]);

    // fused f1/f2 dots on fp32 accumulators
    float a1v[4], a2v[4];
    #pragma unroll
    for (int nt = 0; nt < 4; ++nt) {
        a1v[nt] = a1[bn + (l & 15) + nt * 16];
        a2v[nt] = a2[bn + (l & 15) + nt * 16];
    }
    float p1[4] = {}, p2[4] = {};
    #pragma unroll
    for (int nt = 0; nt < 4; ++nt)
        #pragma unroll
        for (int r = 0; r < 4; ++r) {
            p1[r] += acc[nt][r] * a1v[nt];
            p2[r] += acc[nt][r] * a2v[nt];
        }
    #pragma unroll
    for (int off = 1; off <= 8; off <<= 1)
        #pragma unroll
        for (int r = 0; r < 4; ++r) {
            p1[r] += __shfl_xor(p1[r], off);
            p2[r] += __shfl_xor(p2[r], off);
        }
    if ((l & 15) == 0) {
        int row = bm + w * 16 + (l >> 4) * 4;
        if (layer2) {
            #pragma unroll
            for (int r = 0; r < 4; ++r) {
                atomicAdd(&f1[row + r], p1[r]);
                atomicAdd(&f2[row + r], p2[r]);
            }
        } else {
            #pragma unroll
            for (int r = 0; r < 4; ++r) {
                f1[blockIdx.y * NN + row + r] = p1[r];
                f2[blockIdx.y * NN + row + r] = p2[r];
            }
        }
    }
}

// ---------------------------------------------------------------------------
// Layer-1 sparse attention + ELU + fused (+R, bf16 cast) epilogue.
__global__ __launch_bounds__(512) void att1_kernel(
    const bf16_t* __restrict__ Hbf, const float* __restrict__ f1,
    const float* __restrict__ f2, const int* __restrict__ deg,
    const int* __restrict__ cols, const float* __restrict__ R,
    bf16_t* __restrict__ outbf) {
    int i = blockIdx.x;
    int tid = threadIdx.x;
    int h = tid >> 6;                 // wave id (phase A: head; phase B: slot)
    int l = tid & 63;
    __shared__ int jl[MAXDEG];
    __shared__ float se[NHEADS][MAXDEG];
    __shared__ float part[NHEADS][FEAT];   // 16 KB
    __shared__ float sinv[NHEADS];
    __shared__ int sdeg;
    if (tid == 0) sdeg = deg[i];
    __syncthreads();
    int d = sdeg;
    int dpad = (d + 31) & ~31;        // multiple of 32 (8 waves x 4 unroll)
    for (int k = tid; k < dpad; k += 512)
        jl[k] = (k < d) ? cols[i * MAXDEG + k] : i;   // pad: self, weight 0
    __syncthreads();
    // ---- phase A: scores for head h ----
    float fi = f1[h * NN + i];
    float lmax = -1e30f;
    for (int k = l; k < d; k += 64) {
        float e = fi + f2[h * NN + jl[k]];
        e = e > 0.0f ? e : ALPHA * e;
        se[h][k] = e;
        lmax = fmaxf(lmax, e);
    }
    for (int off = 32; off; off >>= 1) lmax = fmaxf(lmax, __shfl_down(lmax, off));
    float m = __shfl(lmax, 0);
    float ls = 0.0f;
    for (int k = l; k < d; k += 64) {
        float p = __expf(se[h][k] - m);
        se[h][k] = p;
        ls += p;
    }
    for (int k = d + l; k < dpad; k += 64) se[h][k] = 0.0f;
    for (int off = 32; off; off >>= 1) ls += __shfl_down(ls, off);
    if (l == 0) sinv[h] = 1.0f / ls;
    __syncthreads();                  // se/sinv now read cross-wave
    // ---- phase B: whole-row gather (wave h takes k ≡ h mod 8, unroll 4) ----
    const int myhead = l >> 3;        // head of this lane's output columns
    float acc[8] = {};
    for (int k0 = 0; k0 < dpad; k0 += 32) {
        float pw[4];
        const bf16_t* rp[4];
        #pragma unroll
        for (int j = 0; j < 4; ++j) {
            int k = k0 + j * 8 + h;                  // k < dpad guaranteed
            pw[j] = se[myhead][k];
            rp[j] = Hbf + (size_t)jl[k] * FEAT + l * 8;
        }
        #pragma unroll
        for (int j = 0; j < 4; ++j) {
            us8_t v = *(const us8_t*)rp[j];
            float p = pw[j];
            #pragma unroll
            for (int q = 0; q < 8; ++q) acc[q] += p * bfu2f(v[q]);
        }
    }
    *(float4*)&part[h][l * 8]     = make_float4(acc[0], acc[1], acc[2], acc[3]);
    *(float4*)&part[h][l * 8 + 4] = make_float4(acc[4], acc[5], acc[6], acc[7]);
    __syncthreads();
    // ---- epilogue: thread tid handles output column tid ----
    {
        float sum = 0.0f;
        #pragma unroll
        for (int w2 = 0; w2 < NHEADS; ++w2) sum += part[w2][tid];
        float o = sum * sinv[tid >> 6];
        o = o > 0.0f ? o : __expf(o) - 1.0f;         // ELU
        o += R[(size_t)i * FEAT + tid];
        ((unsigned short*)outbf)[(size_t)i * FEAT + tid] = f2bf(o);
    }
}

// ---------------------------------------------------------------------------
// Layer-2 sparse attention + fused classifier + log_softmax. Block = 256.
__global__ __launch_bounds__(256) void att2_final_kernel(
    const bf16_t* __restrict__ Hbf, const float* __restrict__ f1,
    const float* __restrict__ f2, const int* __restrict__ deg,
    const int* __restrict__ cols, const float* __restrict__ linW,
    const float* __restrict__ linb, float* __restrict__ out) {
    int i = blockIdx.x;
    int t = threadIdx.x;
    __shared__ int jl[MAXDEG];
    __shared__ float sp[MAXDEG];
    __shared__ float red[4];
    __shared__ float part[3][FEAT];
    __shared__ float hrow[FEAT];
    __shared__ float clsred[16][NCLS];
    __shared__ float sl[NCLS];
    __shared__ int sdeg;
    if (t == 0) sdeg = deg[i];
    __syncthreads();
    int d = sdeg;
    int dpad = (d + 15) & ~15;        // multiple of 16 (4 waves x 4 unroll)
    if (t < dpad) jl[t] = (t < d) ? cols[i * MAXDEG + t] : i;
    __syncthreads();
    float e = 0.0f, lmax = -1e30f;
    if (t < d) {
        e = f1[i] + f2[jl[t]];
        e = e > 0.0f ? e : ALPHA * e;
        lmax = e;
    }
    for (int off = 32; off; off >>= 1) lmax = fmaxf(lmax, __shfl_down(lmax, off));
    if ((t & 63) == 0) red[t >> 6] = lmax;
    __syncthreads();
    float m = fmaxf(fmaxf(red[0], red[1]), fmaxf(red[2], red[3]));
    float p = 0.0f;
    if (t < d) p = __expf(e - m);
    if (t < dpad) sp[t] = p;          // pads write 0
    float ls = p;
    for (int off = 32; off; off >>= 1) ls += __shfl_down(ls, off);
    __syncthreads();                  // red[] reads done before overwrite
    if ((t & 63) == 0) red[t >> 6] = ls;
    __syncthreads();                  // publishes sp[] + red[]
    float s = red[0] + red[1] + red[2] + red[3];
    float inv = 1.0f / s;
    // whole-row gather, unroll 4
    const int slot = t >> 6;          // 0..3 (wave id)
    const int cg   = t & 63;          // col group (8 bf16)
    float acc[8] = {};
    for (int k0 = 0; k0 < dpad; k0 += 16) {
        float pw[4];
        const bf16_t* rp[4];
        #pragma unroll
        for (int j = 0; j < 4; ++j) {
            int k = k0 + j * 4 + slot;               // k < dpad guaranteed
            pw[j] = sp[k];
            rp[j] = Hbf + (size_t)jl[k] * FEAT + cg * 8;
        }
        #pragma unroll
        for (int j = 0; j < 4; ++j) {
            us8_t v = *(const us8_t*)rp[j];
            float pk = pw[j];
            #pragma unroll
            for (int q = 0; q < 8; ++q) acc[q] += pk * bfu2f(v[q]);
        }
    }
    // combine slots 1..3 into slot 0; slot 0 publishes h2 row to LDS
    if (slot > 0) {
        float* dst = &part[slot - 1][cg * 8];
        *(float4*)(dst)     = make_float4(acc[0], acc[1], acc[2], acc[3]);
        *(float4*)(dst + 4) = make_float4(acc[4], acc[5], acc[6], acc[7]);
    }
    __syncthreads();
    if (slot == 0) {
        #pragma unroll
        for (int sl2 = 0; sl2 < 3; ++sl2)
            #pragma unroll
            for (int j = 0; j < 8; ++j) acc[j] += part[sl2][cg * 8 + j];
        float* dst = &hrow[cg * 8];
        *(float4*)(dst)     = make_float4(acc[0] * inv, acc[1] * inv, acc[2] * inv, acc[3] * inv);
        *(float4*)(dst + 4) = make_float4(acc[4] * inv, acc[5] * inv, acc[6] * inv, acc[7] * inv);
    }
    __syncthreads();
    // classifier: class c = t&15, segment seg = t>>4 (32 features each)
    {
        int c = t & 15;
        int seg = t >> 4;
        float partial = 0.0f;
        int f0 = seg * 32;
        #pragma unroll 8
        for (int f = f0; f < f0 + 32; ++f) partial += hrow[f] * linW[f * NCLS + c];
        clsred[seg][c] = partial;
    }
    __syncthreads();
    if (t < NCLS) {
        float logit = linb[t];
        #pragma unroll
        for (int seg = 0; seg < 16; ++seg) logit += clsred[seg][t];
        logit = logit > 0.0f ? logit : __expf(logit) - 1.0f;   // ELU
        sl[t] = logit;
    }
    __syncthreads();
    if (t < NCLS) {
        float mm = sl[0];
        #pragma unroll
        for (int c = 1; c < NCLS; ++c) mm = fmaxf(mm, sl[c]);
        float ssum = 0.0f;
        #pragma unroll
        for (int c = 0; c < NCLS; ++c) ssum += __expf(sl[c] - mm);
        out[i * NCLS + t] = sl[t] - mm - logf(ssum);
    }
}

// ---------------------------------------------------------------------------
extern "C" void kernel_launch(void* const* d_in, const int* in_sizes, int n_in,
                              void* d_out, int out_size, void* d_ws, size_t ws_size,
                              hipStream_t stream) {
    const float* x        = (const float*)d_in[0];
    const float* rel      = (const float*)d_in[1];
    // d_in[2] rel_dict: unused (non-math constant per reference)
    const float* adj      = (const float*)d_in[3];
    const float* adj_ad   = (const float*)d_in[4];
    const float* W_heads  = (const float*)d_in[5];
    const float* a1_heads = (const float*)d_in[6];
    const float* a2_heads = (const float*)d_in[7];
    const float* W_out    = (const float*)d_in[8];
    const float* a1_out   = (const float*)d_in[9];
    const float* a2_out   = (const float*)d_in[10];
    const float* lin_W    = (const float*)d_in[11];
    const float* lin_b    = (const float*)d_in[12];
    float* out = (float*)d_out;

    char* ws = (char*)d_ws;
    bf16_t* Abf  = (bf16_t*)(ws);                                 // 4 MB  layer-1 GEMM input
    bf16_t* Abf2 = (bf16_t*)(ws + (4u  << 20));                   // 4 MB  layer-2 GEMM input
    bf16_t* Hbf1 = (bf16_t*)(ws + (8u  << 20));                   // 4 MB  layer-1 H (gather)
    bf16_t* Hbf2 = (bf16_t*)(ws + (12u << 20));                   // 4 MB  layer-2 H (gather)
    float*  R    = (float*) (ws + (16u << 20));                   // 8 MB  adj_ad@rel
    bf16_t* WcT  = (bf16_t*)(ws + (24u << 20));                   // 0.5 MB
    bf16_t* WoT  = (bf16_t*)(ws + (24u << 20) + (512u << 10));    // 0.5 MB
    float*  f1   = (float*) (ws + (25u << 20));                   // 128 KB [8,4096]
    float*  f2   = (float*) (ws + (25u << 20) + (128u << 10));    // 128 KB
    float*  f1o  = (float*) (ws + (25u << 20) + (256u << 10));    // 16 KB
    float*  f2o  = (float*) (ws + (25u << 20) + (272u << 10));    // 16 KB
    int*    deg  = (int*)   (ws + (25u << 20) + (288u << 10));    // 16 KB
    int*    cols = (int*)   (ws + (26u << 20));                   // 2 MB  [4096,128]

    // fused front-end: CSR + (R, Abf) + weight permutes + f-zero
    prep_kernel<<<NN + 2048 + 2052, 256, 0, stream>>>(
        adj, deg, cols, adj_ad, rel, x, R, Abf,
        W_heads, W_out, (unsigned short*)WcT, (unsigned short*)WoT, f1o, f2o);
    // layer-1 GEMM + fused f1/f2 dots (direct store)
    gemm_bf16_dot_kernel<<<dim3(64, 8), 256, 0, stream>>>(
        Abf, WcT, (unsigned short*)Hbf1, a1_heads, a2_heads, f1, f2, 0);
    // layer-1 attention + ELU + (+R, bf16) epilogue -> Abf2
    att1_kernel<<<NN, 512, 0, stream>>>(Hbf1, f1, f2, deg, cols, R, Abf2);
    // layer-2 GEMM + fused f1o/f2o dots (atomicAdd across bn blocks)
    gemm_bf16_dot_kernel<<<dim3(64, 8), 256, 0, stream>>>(
        Abf2, WoT, (unsigned short*)Hbf2, a1_out, a2_out, f1o, f2o, 1);
    // layer-2 attention + classifier + log_softmax -> out (fused)
    att2_final_kernel<<<NN, 256, 0, stream>>>(Hbf2, f1o, f2o, deg, cols, lin_W, lin_b, out);
}